// Round 1
// baseline (1281.627 us; speedup 1.0000x reference)
//
#include <hip/hip_runtime.h>

#define NN 100000
#define NE 1600000
#define ET (NE + NN)      // logical edges incl. self-loops
#define NG 256
#define NEG_SLOPE 0.2f
#define SM_EPS 1e-16f

__device__ __forceinline__ void atomicMaxF(float* addr, float v) {
    if (v >= 0.0f) atomicMax((int*)addr, __float_as_int(v));
    else           atomicMin((unsigned int*)addr, __float_as_uint(v));
}

__device__ __forceinline__ float lrelu(float x) { return x > 0.0f ? x : NEG_SLOPE * x; }

// Layer-1 projection (Fin=1) + per-node src/dst attention scores.
// thread per (n,f), f in [0,32)
__global__ void k1_h1_scores(const float* __restrict__ x,
                             const float* __restrict__ W1,
                             const float* __restrict__ a1s,
                             const float* __restrict__ a1d,
                             float* __restrict__ H,
                             float* __restrict__ ss,
                             float* __restrict__ ds) {
    int tid = blockIdx.x * blockDim.x + threadIdx.x;
    if (tid >= NN * 32) return;
    int n = tid >> 5, f = tid & 31;
    float h = x[n] * W1[f];
    H[tid] = h;
    float vs = h * a1s[f];
    float vd = h * a1d[f];
    #pragma unroll
    for (int m = 16; m; m >>= 1) {
        vs += __shfl_xor(vs, m, 32);
        vd += __shfl_xor(vd, m, 32);
    }
    if (f == 0) { ss[n] = vs; ds[n] = vd; }
}

// segment max of leaky_relu(ss[s]+ds[d]) over dst
__global__ void k_edge_max(const int* __restrict__ src, const int* __restrict__ dst,
                           const float* __restrict__ ss, const float* __restrict__ ds,
                           float* __restrict__ amax) {
    int e = blockIdx.x * blockDim.x + threadIdx.x;
    if (e >= ET) return;
    int s, d;
    if (e < NE) { s = src[e]; d = dst[e]; } else { s = e - NE; d = s; }
    float alpha = lrelu(ss[s] + ds[d]);
    atomicMaxF(&amax[d], alpha);
}

// e = exp(alpha - amax[dst]); denom = segment_sum(e)
__global__ void k_edge_expsum(const int* __restrict__ src, const int* __restrict__ dst,
                              const float* __restrict__ ss, const float* __restrict__ ds,
                              const float* __restrict__ amax,
                              float* __restrict__ eal, float* __restrict__ denom) {
    int e = blockIdx.x * blockDim.x + threadIdx.x;
    if (e >= ET) return;
    int s, d;
    if (e < NE) { s = src[e]; d = dst[e]; } else { s = e - NE; d = s; }
    float alpha = lrelu(ss[s] + ds[d]);
    float ev = __expf(alpha - amax[d]);
    eal[e] = ev;
    atomicAdd(&denom[d], ev);
}

// OUT[d] += H[s] * w, thread per (edge, feature). F = 1<<LOGF
template<int LOGF>
__global__ void k_edge_agg(const int* __restrict__ src, const int* __restrict__ dst,
                           const float* __restrict__ eal, const float* __restrict__ denom,
                           const float* __restrict__ H, float* __restrict__ OUT) {
    const int F = 1 << LOGF;
    int tid = blockIdx.x * blockDim.x + threadIdx.x;
    int e = tid >> LOGF;
    if (e >= ET) return;
    int f = tid & (F - 1);
    int s, d;
    if (e < NE) { s = src[e]; d = dst[e]; } else { s = e - NE; d = s; }
    float w = eal[e] / (denom[d] + SM_EPS);
    atomicAdd(&OUT[d * F + f], H[s * F + f] * w);
}

// x2 = relu(OUT1 + b1); H2 = x2 @ W2; ss2/ds2 = H2·a2s / H2·a2d
// one wave (64 lanes) per node, lane = output feature
__global__ void k5_h2(const float* __restrict__ OUT1,  // N x 32
                      const float* __restrict__ b1,
                      const float* __restrict__ W2,    // 32 x 64
                      const float* __restrict__ a2s, const float* __restrict__ a2d,
                      float* __restrict__ H2,
                      float* __restrict__ ss, float* __restrict__ ds) {
    __shared__ float w2s[32 * 64];
    __shared__ float b1s[32];
    int t = threadIdx.x;
    for (int i = t; i < 32 * 64; i += 256) w2s[i] = W2[i];
    if (t < 32) b1s[t] = b1[t];
    __syncthreads();
    int idx = blockIdx.x * 256 + t;
    int n = idx >> 6, f = idx & 63;
    if (n >= NN) return;
    float acc = 0.0f;
    #pragma unroll
    for (int k = 0; k < 32; ++k) {
        float xv = OUT1[n * 32 + k] + b1s[k];
        xv = xv > 0.0f ? xv : 0.0f;
        acc += xv * w2s[k * 64 + f];
    }
    H2[n * 64 + f] = acc;
    float vs = acc * a2s[f];
    float vd = acc * a2d[f];
    #pragma unroll
    for (int m = 32; m; m >>= 1) {
        vs += __shfl_xor(vs, m, 64);
        vd += __shfl_xor(vd, m, 64);
    }
    if (f == 0) { ss[n] = vs; ds[n] = vd; }
}

// relu(OUT2 + b2) -> atomic segment-sum into pooled[g][f], counts
__global__ void k6_pool(const float* __restrict__ OUT2, const float* __restrict__ b2,
                        const int* __restrict__ batch,
                        float* __restrict__ pooled, float* __restrict__ cnts) {
    int tid = blockIdx.x * blockDim.x + threadIdx.x;
    if (tid >= NN * 64) return;
    int n = tid >> 6, f = tid & 63;
    float v = OUT2[tid] + b2[f];
    v = v > 0.0f ? v : 0.0f;
    int g = batch[n];
    atomicAdd(&pooled[g * 64 + f], v);
    if (f == 0) atomicAdd(&cnts[g], 1.0f);
}

// out[g] = (pooled[g]/max(cnt,1)) @ fcW + fcb
__global__ void k7_fc(const float* __restrict__ pooled, const float* __restrict__ cnts,
                      const float* __restrict__ fcW, const float* __restrict__ fcb,
                      float* __restrict__ out) {
    int g = threadIdx.x;
    if (g >= NG) return;
    float c = fmaxf(cnts[g], 1.0f);
    float o0 = fcb[0], o1 = fcb[1];
    for (int f = 0; f < 64; ++f) {
        float p = pooled[g * 64 + f] / c;
        o0 += p * fcW[f * 2 + 0];
        o1 += p * fcW[f * 2 + 1];
    }
    out[g * 2 + 0] = o0;
    out[g * 2 + 1] = o1;
}

extern "C" void kernel_launch(void* const* d_in, const int* in_sizes, int n_in,
                              void* d_out, int out_size, void* d_ws, size_t ws_size,
                              hipStream_t stream) {
    const float* x    = (const float*)d_in[0];
    const int*   ei   = (const int*)d_in[1];
    const int*   src  = ei;
    const int*   dst  = ei + NE;
    const int*   batch= (const int*)d_in[2];
    const float* W1   = (const float*)d_in[3];
    const float* a1s  = (const float*)d_in[4];
    const float* a1d  = (const float*)d_in[5];
    const float* b1   = (const float*)d_in[6];
    const float* W2   = (const float*)d_in[7];
    const float* a2s  = (const float*)d_in[8];
    const float* a2d  = (const float*)d_in[9];
    const float* b2   = (const float*)d_in[10];
    const float* fcW  = (const float*)d_in[11];
    const float* fcb  = (const float*)d_in[12];
    float* out = (float*)d_out;

    float* ws = (float*)d_ws;
    float* scoreS = ws;                 // NN
    float* scoreD = scoreS + NN;        // NN
    float* amax   = scoreD + NN;        // NN
    float* denom  = amax + NN;          // NN
    float* H      = denom + NN;         // NN*64
    float* OUT    = H + (size_t)NN * 64;// NN*64
    float* eal    = OUT + (size_t)NN * 64; // ET
    float* pooled = eal + ET;           // NG*64
    float* cnts   = pooled + NG * 64;   // NG

    const int B = 256;
    int gridE = (ET + B - 1) / B;

    // ---------------- layer 1 (F=32) ----------------
    hipMemsetAsync(amax, 0xFF, (size_t)NN * 4, stream);   // NaN-bits; replaced by first atomicMaxF
    hipMemsetAsync(denom, 0, (size_t)NN * 4, stream);
    hipMemsetAsync(OUT, 0, (size_t)NN * 32 * 4, stream);

    k1_h1_scores<<<(NN * 32 + B - 1) / B, B, 0, stream>>>(x, W1, a1s, a1d, H, scoreS, scoreD);
    k_edge_max<<<gridE, B, 0, stream>>>(src, dst, scoreS, scoreD, amax);
    k_edge_expsum<<<gridE, B, 0, stream>>>(src, dst, scoreS, scoreD, amax, eal, denom);
    k_edge_agg<5><<<((size_t)ET * 32 + B - 1) / B, B, 0, stream>>>(src, dst, eal, denom, H, OUT);

    // ---------------- layer 2 projection (reads OUT before re-zero) ----------------
    k5_h2<<<(NN * 64 + B - 1) / B, B, 0, stream>>>(OUT, b1, W2, a2s, a2d, H, scoreS, scoreD);

    // ---------------- layer 2 (F=64) ----------------
    hipMemsetAsync(amax, 0xFF, (size_t)NN * 4, stream);
    hipMemsetAsync(denom, 0, (size_t)NN * 4, stream);
    hipMemsetAsync(OUT, 0, (size_t)NN * 64 * 4, stream);

    k_edge_max<<<gridE, B, 0, stream>>>(src, dst, scoreS, scoreD, amax);
    k_edge_expsum<<<gridE, B, 0, stream>>>(src, dst, scoreS, scoreD, amax, eal, denom);
    k_edge_agg<6><<<((size_t)ET * 64 + B - 1) / B, B, 0, stream>>>(src, dst, eal, denom, H, OUT);

    // ---------------- pool + fc ----------------
    hipMemsetAsync(pooled, 0, (size_t)(NG * 64 + NG) * 4, stream);
    k6_pool<<<(NN * 64 + B - 1) / B, B, 0, stream>>>(OUT, b2, batch, pooled, cnts);
    k7_fc<<<1, B, 0, stream>>>(pooled, cnts, fcW, fcb, out);
}

// Round 2
// 1003.363 us; speedup vs baseline: 1.2773x; 1.2773x over previous
//
#include <hip/hip_runtime.h>

#define NN 100000
#define NE 1600000
#define ET (NE + NN)      // logical edges incl. self-loops
#define NG 256
#define NEG_SLOPE 0.2f
#define SM_EPS 1e-16f

#define SCAN_B 256
#define NCHUNK ((NN + SCAN_B - 1) / SCAN_B)   // 391

__device__ __forceinline__ float lrelu(float x) { return x > 0.0f ? x : NEG_SLOPE * x; }

// ---------------- CSR build ----------------
__global__ void k_hist(const int* __restrict__ dst, int* __restrict__ deg) {
    int e = blockIdx.x * blockDim.x + threadIdx.x;
    if (e >= ET) return;
    int d = (e < NE) ? dst[e] : (e - NE);
    atomicAdd(&deg[d], 1);
}

__global__ void k_scan_a(const int* __restrict__ deg, int* __restrict__ bsum) {
    __shared__ int sm[SCAN_B];
    int b = blockIdx.x, t = threadIdx.x;
    int i = b * SCAN_B + t;
    sm[t] = (i < NN) ? deg[i] : 0;
    __syncthreads();
    for (int s = SCAN_B / 2; s; s >>= 1) {
        if (t < s) sm[t] += sm[t + s];
        __syncthreads();
    }
    if (t == 0) bsum[b] = sm[0];
}

__global__ void k_scan_b(int* __restrict__ bsum) {   // 1 block, 512 threads
    __shared__ int sm[512];
    int t = threadIdx.x;
    sm[t] = (t < NCHUNK) ? bsum[t] : 0;
    __syncthreads();
    for (int off = 1; off < 512; off <<= 1) {
        int v = (t >= off) ? sm[t - off] : 0;
        __syncthreads();
        sm[t] += v;
        __syncthreads();
    }
    if (t < NCHUNK) bsum[t] = (t == 0) ? 0 : sm[t - 1];   // exclusive
}

__global__ void k_scan_c(const int* __restrict__ deg, const int* __restrict__ bsum,
                         int* __restrict__ row_start, int* __restrict__ cursor) {
    __shared__ int sm[SCAN_B];
    int b = blockIdx.x, t = threadIdx.x;
    int i = b * SCAN_B + t;
    int v = (i < NN) ? deg[i] : 0;
    sm[t] = v;
    __syncthreads();
    for (int off = 1; off < SCAN_B; off <<= 1) {
        int u = (t >= off) ? sm[t - off] : 0;
        __syncthreads();
        sm[t] += u;
        __syncthreads();
    }
    if (i < NN) {
        int excl = sm[t] - v + bsum[b];
        row_start[i] = excl;
        cursor[i] = excl;
    }
}

__global__ void k_scatter(const int* __restrict__ src, const int* __restrict__ dst,
                          int* __restrict__ cursor, int* __restrict__ csr_src) {
    int e = blockIdx.x * blockDim.x + threadIdx.x;
    if (e >= ET) return;
    int s, d;
    if (e < NE) { s = src[e]; d = dst[e]; } else { s = e - NE; d = s; }
    int pos = atomicAdd(&cursor[d], 1);
    csr_src[pos] = s;
}

// ---------------- layer 1 projection + scores ----------------
__global__ void k1_h1_scores(const float* __restrict__ x,
                             const float* __restrict__ W1,
                             const float* __restrict__ a1s,
                             const float* __restrict__ a1d,
                             float* __restrict__ H,
                             float* __restrict__ ss,
                             float* __restrict__ ds) {
    int tid = blockIdx.x * blockDim.x + threadIdx.x;
    if (tid >= NN * 32) return;
    int n = tid >> 5, f = tid & 31;
    float h = x[n] * W1[f];
    H[tid] = h;
    float vs = h * a1s[f];
    float vd = h * a1d[f];
    #pragma unroll
    for (int m = 16; m; m >>= 1) {
        vs += __shfl_xor(vs, m, 32);
        vd += __shfl_xor(vd, m, 32);
    }
    if (f == 0) { ss[n] = vs; ds[n] = vd; }
}

// ---------------- fused per-node GAT layer (softmax + aggregate) ----------------
// one 64-lane wave per destination node; F = 1<<LOGF features
template<int LOGF>
__global__ void k_gat_node(const int* __restrict__ row_start, const int* __restrict__ deg,
                           const int* __restrict__ csr_src,
                           const float* __restrict__ ss, const float* __restrict__ ds,
                           const float* __restrict__ H, float* __restrict__ OUT) {
    const int F = 1 << LOGF;
    int wid = (blockIdx.x * blockDim.x + threadIdx.x) >> 6;
    int lane = threadIdx.x & 63;
    if (wid >= NN) return;
    int start = row_start[wid];
    int dg = deg[wid];
    float dsv = ds[wid];

    // pass 1: segment max (lanes parallel over edges)
    float m = -1e30f;
    for (int i = lane; i < dg; i += 64) {
        int s = csr_src[start + i];
        m = fmaxf(m, lrelu(ss[s] + dsv));
    }
    #pragma unroll
    for (int o = 32; o; o >>= 1) m = fmaxf(m, __shfl_xor(m, o, 64));

    // pass 2: exp-sum
    float sum = 0.0f;
    for (int i = lane; i < dg; i += 64) {
        int s = csr_src[start + i];
        sum += __expf(lrelu(ss[s] + dsv) - m);
    }
    #pragma unroll
    for (int o = 32; o; o >>= 1) sum += __shfl_xor(sum, o, 64);
    float inv = 1.0f / (sum + SM_EPS);

    // pass 3: weighted aggregate, lane = feature, serial over edges
    float acc = 0.0f;
    for (int i = 0; i < dg; ++i) {
        int s = csr_src[start + i];                    // uniform across lanes
        float ev = __expf(lrelu(ss[s] + dsv) - m);     // redundant per lane, cheap
        if (lane < F) acc += ev * H[(size_t)s * F + lane];
    }
    if (lane < F) OUT[(size_t)wid * F + lane] = acc * inv;
}

// ---------------- layer 2 projection + scores ----------------
__global__ void k5_h2(const float* __restrict__ OUT1,  // N x 32
                      const float* __restrict__ b1,
                      const float* __restrict__ W2,    // 32 x 64
                      const float* __restrict__ a2s, const float* __restrict__ a2d,
                      float* __restrict__ H2,
                      float* __restrict__ ss, float* __restrict__ ds) {
    __shared__ float w2s[32 * 64];
    __shared__ float b1s[32];
    int t = threadIdx.x;
    for (int i = t; i < 32 * 64; i += 256) w2s[i] = W2[i];
    if (t < 32) b1s[t] = b1[t];
    __syncthreads();
    int idx = blockIdx.x * 256 + t;
    int n = idx >> 6, f = idx & 63;
    if (n >= NN) return;
    float acc = 0.0f;
    #pragma unroll
    for (int k = 0; k < 32; ++k) {
        float xv = OUT1[n * 32 + k] + b1s[k];
        xv = xv > 0.0f ? xv : 0.0f;
        acc += xv * w2s[k * 64 + f];
    }
    H2[n * 64 + f] = acc;
    float vs = acc * a2s[f];
    float vd = acc * a2d[f];
    #pragma unroll
    for (int m = 32; m; m >>= 1) {
        vs += __shfl_xor(vs, m, 64);
        vd += __shfl_xor(vd, m, 64);
    }
    if (f == 0) { ss[n] = vs; ds[n] = vd; }
}

// ---------------- pool + fc ----------------
__global__ void k6_pool(const float* __restrict__ OUT2, const float* __restrict__ b2,
                        const int* __restrict__ batch,
                        float* __restrict__ pooled, float* __restrict__ cnts) {
    int tid = blockIdx.x * blockDim.x + threadIdx.x;
    if (tid >= NN * 64) return;
    int n = tid >> 6, f = tid & 63;
    float v = OUT2[tid] + b2[f];
    v = v > 0.0f ? v : 0.0f;
    int g = batch[n];
    atomicAdd(&pooled[g * 64 + f], v);
    if (f == 0) atomicAdd(&cnts[g], 1.0f);
}

__global__ void k7_fc(const float* __restrict__ pooled, const float* __restrict__ cnts,
                      const float* __restrict__ fcW, const float* __restrict__ fcb,
                      float* __restrict__ out) {
    int g = threadIdx.x;
    if (g >= NG) return;
    float c = fmaxf(cnts[g], 1.0f);
    float o0 = fcb[0], o1 = fcb[1];
    for (int f = 0; f < 64; ++f) {
        float p = pooled[g * 64 + f] / c;
        o0 += p * fcW[f * 2 + 0];
        o1 += p * fcW[f * 2 + 1];
    }
    out[g * 2 + 0] = o0;
    out[g * 2 + 1] = o1;
}

extern "C" void kernel_launch(void* const* d_in, const int* in_sizes, int n_in,
                              void* d_out, int out_size, void* d_ws, size_t ws_size,
                              hipStream_t stream) {
    const float* x    = (const float*)d_in[0];
    const int*   ei   = (const int*)d_in[1];
    const int*   src  = ei;
    const int*   dst  = ei + NE;
    const int*   batch= (const int*)d_in[2];
    const float* W1   = (const float*)d_in[3];
    const float* a1s  = (const float*)d_in[4];
    const float* a1d  = (const float*)d_in[5];
    const float* b1   = (const float*)d_in[6];
    const float* W2   = (const float*)d_in[7];
    const float* a2s  = (const float*)d_in[8];
    const float* a2d  = (const float*)d_in[9];
    const float* b2   = (const float*)d_in[10];
    const float* fcW  = (const float*)d_in[11];
    const float* fcb  = (const float*)d_in[12];
    float* out = (float*)d_out;

    int* deg       = (int*)d_ws;            // NN
    int* row_start = deg + NN;              // NN
    int* cursor    = row_start + NN;        // NN
    int* bsum      = cursor + NN;           // 512
    int* csr_src   = bsum + 512;            // ET
    float* scoreS  = (float*)(csr_src + ET);// NN
    float* scoreD  = scoreS + NN;           // NN
    float* H       = scoreD + NN;           // NN*64
    float* OUT     = H + (size_t)NN * 64;   // NN*64
    float* pooled  = OUT + (size_t)NN * 64; // NG*64
    float* cnts    = pooled + NG * 64;      // NG

    const int B = 256;
    int gridE = (ET + B - 1) / B;
    int gridW = (NN * 64 + B - 1) / B;      // wave-per-node kernels

    // ---- CSR build (shared by both layers) ----
    hipMemsetAsync(deg, 0, (size_t)NN * 4, stream);
    k_hist<<<gridE, B, 0, stream>>>(dst, deg);
    k_scan_a<<<NCHUNK, SCAN_B, 0, stream>>>(deg, bsum);
    k_scan_b<<<1, 512, 0, stream>>>(bsum);
    k_scan_c<<<NCHUNK, SCAN_B, 0, stream>>>(deg, bsum, row_start, cursor);
    k_scatter<<<gridE, B, 0, stream>>>(src, dst, cursor, csr_src);

    // ---- layer 1 (F=32) ----
    k1_h1_scores<<<(NN * 32 + B - 1) / B, B, 0, stream>>>(x, W1, a1s, a1d, H, scoreS, scoreD);
    k_gat_node<5><<<gridW, B, 0, stream>>>(row_start, deg, csr_src, scoreS, scoreD, H, OUT);

    // ---- layer 2 projection ----
    k5_h2<<<gridW, B, 0, stream>>>(OUT, b1, W2, a2s, a2d, H, scoreS, scoreD);

    // ---- layer 2 (F=64) ----
    k_gat_node<6><<<gridW, B, 0, stream>>>(row_start, deg, csr_src, scoreS, scoreD, H, OUT);

    // ---- pool + fc ----
    hipMemsetAsync(pooled, 0, (size_t)(NG * 64 + NG) * 4, stream);
    k6_pool<<<gridW, B, 0, stream>>>(OUT, b2, batch, pooled, cnts);
    k7_fc<<<1, B, 0, stream>>>(pooled, cnts, fcW, fcb, out);
}

// Round 3
// 656.502 us; speedup vs baseline: 1.9522x; 1.5283x over previous
//
#include <hip/hip_runtime.h>

#define NN 100000
#define NE 1600000
#define ET (NE + NN)      // logical edges incl. self-loops
#define NG 256
#define NEG_SLOPE 0.2f
#define SM_EPS 1e-16f

#define SCAN_B 256
#define NCHUNK ((NN + SCAN_B - 1) / SCAN_B)   // 391

__device__ __forceinline__ float lrelu(float x) { return x > 0.0f ? x : NEG_SLOPE * x; }

// ---------------- CSR build ----------------
__global__ void k_hist(const int* __restrict__ dst, int* __restrict__ deg) {
    int e = blockIdx.x * blockDim.x + threadIdx.x;
    if (e >= ET) return;
    int d = (e < NE) ? dst[e] : (e - NE);
    atomicAdd(&deg[d], 1);
}

__global__ void k_scan_a(const int* __restrict__ deg, int* __restrict__ bsum) {
    __shared__ int sm[SCAN_B];
    int b = blockIdx.x, t = threadIdx.x;
    int i = b * SCAN_B + t;
    sm[t] = (i < NN) ? deg[i] : 0;
    __syncthreads();
    for (int s = SCAN_B / 2; s; s >>= 1) {
        if (t < s) sm[t] += sm[t + s];
        __syncthreads();
    }
    if (t == 0) bsum[b] = sm[0];
}

__global__ void k_scan_b(int* __restrict__ bsum) {   // 1 block, 512 threads
    __shared__ int sm[512];
    int t = threadIdx.x;
    sm[t] = (t < NCHUNK) ? bsum[t] : 0;
    __syncthreads();
    for (int off = 1; off < 512; off <<= 1) {
        int v = (t >= off) ? sm[t - off] : 0;
        __syncthreads();
        sm[t] += v;
        __syncthreads();
    }
    if (t < NCHUNK) bsum[t] = (t == 0) ? 0 : sm[t - 1];   // exclusive
}

__global__ void k_scan_c(const int* __restrict__ deg, const int* __restrict__ bsum,
                         int* __restrict__ row_start, int* __restrict__ cursor) {
    __shared__ int sm[SCAN_B];
    int b = blockIdx.x, t = threadIdx.x;
    int i = b * SCAN_B + t;
    int v = (i < NN) ? deg[i] : 0;
    sm[t] = v;
    __syncthreads();
    for (int off = 1; off < SCAN_B; off <<= 1) {
        int u = (t >= off) ? sm[t - off] : 0;
        __syncthreads();
        sm[t] += u;
        __syncthreads();
    }
    if (i < NN) {
        int excl = sm[t] - v + bsum[b];
        row_start[i] = excl;
        cursor[i] = excl;
    }
}

__global__ void k_scatter(const int* __restrict__ src, const int* __restrict__ dst,
                          int* __restrict__ cursor, int* __restrict__ csr_src) {
    int e = blockIdx.x * blockDim.x + threadIdx.x;
    if (e >= ET) return;
    int s, d;
    if (e < NE) { s = src[e]; d = dst[e]; } else { s = e - NE; d = s; }
    int pos = atomicAdd(&cursor[d], 1);
    csr_src[pos] = s;
}

// ---------------- layer 1 projection + scores ----------------
__global__ void k1_h1_scores(const float* __restrict__ x,
                             const float* __restrict__ W1,
                             const float* __restrict__ a1s,
                             const float* __restrict__ a1d,
                             float* __restrict__ H,
                             float* __restrict__ ss,
                             float* __restrict__ ds) {
    int tid = blockIdx.x * blockDim.x + threadIdx.x;
    if (tid >= NN * 32) return;
    int n = tid >> 5, f = tid & 31;
    float h = x[n] * W1[f];
    H[tid] = h;
    float vs = h * a1s[f];
    float vd = h * a1d[f];
    #pragma unroll
    for (int m = 16; m; m >>= 1) {
        vs += __shfl_xor(vs, m, 32);
        vd += __shfl_xor(vd, m, 32);
    }
    if (f == 0) { ss[n] = vs; ds[n] = vd; }
}

// ---------------- fused per-node GAT layer (softmax + aggregate) ----------------
// one 64-lane wave per destination node; F = 1<<LOGF features
template<int LOGF>
__global__ void k_gat_node(const int* __restrict__ row_start, const int* __restrict__ deg,
                           const int* __restrict__ csr_src,
                           const float* __restrict__ ss, const float* __restrict__ ds,
                           const float* __restrict__ H, float* __restrict__ OUT) {
    const int F = 1 << LOGF;
    int wid = (blockIdx.x * blockDim.x + threadIdx.x) >> 6;
    int lane = threadIdx.x & 63;
    if (wid >= NN) return;
    int start = row_start[wid];
    int dg = deg[wid];
    float dsv = ds[wid];

    // pass 1: segment max (lanes parallel over edges)
    float m = -1e30f;
    for (int i = lane; i < dg; i += 64) {
        int s = csr_src[start + i];
        m = fmaxf(m, lrelu(ss[s] + dsv));
    }
    #pragma unroll
    for (int o = 32; o; o >>= 1) m = fmaxf(m, __shfl_xor(m, o, 64));

    // pass 2: exp-sum
    float sum = 0.0f;
    for (int i = lane; i < dg; i += 64) {
        int s = csr_src[start + i];
        sum += __expf(lrelu(ss[s] + dsv) - m);
    }
    #pragma unroll
    for (int o = 32; o; o >>= 1) sum += __shfl_xor(sum, o, 64);
    float inv = 1.0f / (sum + SM_EPS);

    // pass 3: weighted aggregate, lane = feature, serial over edges
    float acc = 0.0f;
    for (int i = 0; i < dg; ++i) {
        int s = csr_src[start + i];                    // uniform across lanes
        float ev = __expf(lrelu(ss[s] + dsv) - m);     // redundant per lane, cheap
        if (lane < F) acc += ev * H[(size_t)s * F + lane];
    }
    if (lane < F) OUT[(size_t)wid * F + lane] = acc * inv;
}

// ---------------- layer 2 projection + scores ----------------
__global__ void k5_h2(const float* __restrict__ OUT1,  // N x 32
                      const float* __restrict__ b1,
                      const float* __restrict__ W2,    // 32 x 64
                      const float* __restrict__ a2s, const float* __restrict__ a2d,
                      float* __restrict__ H2,
                      float* __restrict__ ss, float* __restrict__ ds) {
    __shared__ float w2s[32 * 64];
    __shared__ float b1s[32];
    int t = threadIdx.x;
    for (int i = t; i < 32 * 64; i += 256) w2s[i] = W2[i];
    if (t < 32) b1s[t] = b1[t];
    __syncthreads();
    int idx = blockIdx.x * 256 + t;
    int n = idx >> 6, f = idx & 63;
    if (n >= NN) return;
    float acc = 0.0f;
    #pragma unroll
    for (int k = 0; k < 32; ++k) {
        float xv = OUT1[n * 32 + k] + b1s[k];
        xv = xv > 0.0f ? xv : 0.0f;
        acc += xv * w2s[k * 64 + f];
    }
    H2[n * 64 + f] = acc;
    float vs = acc * a2s[f];
    float vd = acc * a2d[f];
    #pragma unroll
    for (int m = 32; m; m >>= 1) {
        vs += __shfl_xor(vs, m, 64);
        vd += __shfl_xor(vd, m, 64);
    }
    if (f == 0) { ss[n] = vs; ds[n] = vd; }
}

// ---------------- pool (segmented, low-contention) + fc ----------------
// one wave per 64-node contiguous chunk; lane = feature; batch is sorted,
// so flush atomics only at graph boundaries within the chunk.
#define POOL_CHUNK 64
__global__ void k6_pool(const float* __restrict__ OUT2, const float* __restrict__ b2,
                        const int* __restrict__ batch,
                        float* __restrict__ pooled, float* __restrict__ cnts) {
    int wid = (blockIdx.x * blockDim.x + threadIdx.x) >> 6;
    int lane = threadIdx.x & 63;
    int n0 = wid * POOL_CHUNK;
    if (n0 >= NN) return;
    int n1 = n0 + POOL_CHUNK; if (n1 > NN) n1 = NN;
    float bv = b2[lane];
    int curg = batch[n0];
    float acc = 0.0f;
    int cnt = 0;
    for (int n = n0; n < n1; ++n) {
        int g = batch[n];                       // wave-uniform
        if (g != curg) {
            atomicAdd(&pooled[curg * 64 + lane], acc);
            if (lane == 0) atomicAdd(&cnts[curg], (float)cnt);
            acc = 0.0f; cnt = 0; curg = g;
        }
        float v = OUT2[(size_t)n * 64 + lane] + bv;
        acc += v > 0.0f ? v : 0.0f;
        ++cnt;
    }
    atomicAdd(&pooled[curg * 64 + lane], acc);
    if (lane == 0) atomicAdd(&cnts[curg], (float)cnt);
}

__global__ void k7_fc(const float* __restrict__ pooled, const float* __restrict__ cnts,
                      const float* __restrict__ fcW, const float* __restrict__ fcb,
                      float* __restrict__ out) {
    int g = threadIdx.x;
    if (g >= NG) return;
    float c = fmaxf(cnts[g], 1.0f);
    float o0 = fcb[0], o1 = fcb[1];
    for (int f = 0; f < 64; ++f) {
        float p = pooled[g * 64 + f] / c;
        o0 += p * fcW[f * 2 + 0];
        o1 += p * fcW[f * 2 + 1];
    }
    out[g * 2 + 0] = o0;
    out[g * 2 + 1] = o1;
}

extern "C" void kernel_launch(void* const* d_in, const int* in_sizes, int n_in,
                              void* d_out, int out_size, void* d_ws, size_t ws_size,
                              hipStream_t stream) {
    const float* x    = (const float*)d_in[0];
    const int*   ei   = (const int*)d_in[1];
    const int*   src  = ei;
    const int*   dst  = ei + NE;
    const int*   batch= (const int*)d_in[2];
    const float* W1   = (const float*)d_in[3];
    const float* a1s  = (const float*)d_in[4];
    const float* a1d  = (const float*)d_in[5];
    const float* b1   = (const float*)d_in[6];
    const float* W2   = (const float*)d_in[7];
    const float* a2s  = (const float*)d_in[8];
    const float* a2d  = (const float*)d_in[9];
    const float* b2   = (const float*)d_in[10];
    const float* fcW  = (const float*)d_in[11];
    const float* fcb  = (const float*)d_in[12];
    float* out = (float*)d_out;

    int* deg       = (int*)d_ws;            // NN
    int* row_start = deg + NN;              // NN
    int* cursor    = row_start + NN;        // NN
    int* bsum      = cursor + NN;           // 512
    int* csr_src   = bsum + 512;            // ET
    float* scoreS  = (float*)(csr_src + ET);// NN
    float* scoreD  = scoreS + NN;           // NN
    float* H       = scoreD + NN;           // NN*64
    float* OUT     = H + (size_t)NN * 64;   // NN*64
    float* pooled  = OUT + (size_t)NN * 64; // NG*64
    float* cnts    = pooled + NG * 64;      // NG

    const int B = 256;
    int gridE = (ET + B - 1) / B;
    int gridW = (NN * 64 + B - 1) / B;      // wave-per-node kernels

    // ---- CSR build (shared by both layers) ----
    hipMemsetAsync(deg, 0, (size_t)NN * 4, stream);
    k_hist<<<gridE, B, 0, stream>>>(dst, deg);
    k_scan_a<<<NCHUNK, SCAN_B, 0, stream>>>(deg, bsum);
    k_scan_b<<<1, 512, 0, stream>>>(bsum);
    k_scan_c<<<NCHUNK, SCAN_B, 0, stream>>>(deg, bsum, row_start, cursor);
    k_scatter<<<gridE, B, 0, stream>>>(src, dst, cursor, csr_src);

    // ---- layer 1 (F=32) ----
    k1_h1_scores<<<(NN * 32 + B - 1) / B, B, 0, stream>>>(x, W1, a1s, a1d, H, scoreS, scoreD);
    k_gat_node<5><<<gridW, B, 0, stream>>>(row_start, deg, csr_src, scoreS, scoreD, H, OUT);

    // ---- layer 2 projection ----
    k5_h2<<<gridW, B, 0, stream>>>(OUT, b1, W2, a2s, a2d, H, scoreS, scoreD);

    // ---- layer 2 (F=64) ----
    k_gat_node<6><<<gridW, B, 0, stream>>>(row_start, deg, csr_src, scoreS, scoreD, H, OUT);

    // ---- pool + fc ----
    hipMemsetAsync(pooled, 0, (size_t)(NG * 64 + NG) * 4, stream);
    int gridP = ((NN + POOL_CHUNK - 1) / POOL_CHUNK * 64 + B - 1) / B;
    k6_pool<<<gridP, B, 0, stream>>>(OUT, b2, batch, pooled, cnts);
    k7_fc<<<1, B, 0, stream>>>(pooled, cnts, fcW, fcb, out);
}

// Round 5
// 411.896 us; speedup vs baseline: 3.1115x; 1.5939x over previous
//
#include <hip/hip_runtime.h>

#define NN 100000
#define NE 1600000
#define ET (NE + NN)      // logical edges incl. self-loops
#define NG 256
#define NEG_SLOPE 0.2f
#define SM_EPS 1e-16f

#define SCAN_B 256
#define NCHUNK ((NN + SCAN_B - 1) / SCAN_B)   // 391

__device__ __forceinline__ float lrelu(float x) { return x > 0.0f ? x : NEG_SLOPE * x; }

// ---------------- CSR build ----------------
__global__ void k_hist(const int* __restrict__ dst, int* __restrict__ deg) {
    int e = blockIdx.x * blockDim.x + threadIdx.x;
    if (e >= ET) return;
    int d = (e < NE) ? dst[e] : (e - NE);
    atomicAdd(&deg[d], 1);
}

__global__ void k_scan_a(const int* __restrict__ deg, int* __restrict__ bsum) {
    __shared__ int sm[SCAN_B];
    int b = blockIdx.x, t = threadIdx.x;
    int i = b * SCAN_B + t;
    sm[t] = (i < NN) ? deg[i] : 0;
    __syncthreads();
    for (int s = SCAN_B / 2; s; s >>= 1) {
        if (t < s) sm[t] += sm[t + s];
        __syncthreads();
    }
    if (t == 0) bsum[b] = sm[0];
}

__global__ void k_scan_b(int* __restrict__ bsum) {   // 1 block, 512 threads
    __shared__ int sm[512];
    int t = threadIdx.x;
    sm[t] = (t < NCHUNK) ? bsum[t] : 0;
    __syncthreads();
    for (int off = 1; off < 512; off <<= 1) {
        int v = (t >= off) ? sm[t - off] : 0;
        __syncthreads();
        sm[t] += v;
        __syncthreads();
    }
    if (t < NCHUNK) bsum[t] = (t == 0) ? 0 : sm[t - 1];   // exclusive
}

__global__ void k_scan_c(const int* __restrict__ deg, const int* __restrict__ bsum,
                         int* __restrict__ row_start, int* __restrict__ cursor) {
    __shared__ int sm[SCAN_B];
    int b = blockIdx.x, t = threadIdx.x;
    int i = b * SCAN_B + t;
    int v = (i < NN) ? deg[i] : 0;
    sm[t] = v;
    __syncthreads();
    for (int off = 1; off < SCAN_B; off <<= 1) {
        int u = (t >= off) ? sm[t - off] : 0;
        __syncthreads();
        sm[t] += u;
        __syncthreads();
    }
    if (i < NN) {
        int excl = sm[t] - v + bsum[b];
        row_start[i] = excl;
        cursor[i] = excl;
    }
}

__global__ void k_scatter(const int* __restrict__ src, const int* __restrict__ dst,
                          int* __restrict__ cursor, int* __restrict__ csr_src) {
    int e = blockIdx.x * blockDim.x + threadIdx.x;
    if (e >= ET) return;
    int s, d;
    if (e < NE) { s = src[e]; d = dst[e]; } else { s = e - NE; d = s; }
    int pos = atomicAdd(&cursor[d], 1);
    csr_src[pos] = s;
}

// ---------------- layer 1 projection + scores ----------------
__global__ void k1_h1_scores(const float* __restrict__ x,
                             const float* __restrict__ W1,
                             const float* __restrict__ a1s,
                             const float* __restrict__ a1d,
                             float* __restrict__ H,
                             float* __restrict__ ss,
                             float* __restrict__ ds) {
    int tid = blockIdx.x * blockDim.x + threadIdx.x;
    if (tid >= NN * 32) return;
    int n = tid >> 5, f = tid & 31;
    float h = x[n] * W1[f];
    H[tid] = h;
    float vs = h * a1s[f];
    float vd = h * a1d[f];
    #pragma unroll
    for (int m = 16; m; m >>= 1) {
        vs += __shfl_xor(vs, m, 32);
        vd += __shfl_xor(vd, m, 32);
    }
    if (f == 0) { ss[n] = vs; ds[n] = vd; }
}

// ---------------- fused per-node GAT layer (softmax + aggregate) ----------------
// one 64-lane wave per destination node; F = 1<<LOGF features.
// pass 1 caches src idx + alpha for the first 64 edges in registers;
// pass 3 processes GRP edges concurrently (lane = (edge group, float4 of features)).
// CRITICAL: all __shfl calls execute with ALL 64 lanes active (uniform trip
// count), since shfl from an inactive source lane is undefined on CDNA.
template<int LOGF>
__global__ void k_gat_node(const int* __restrict__ row_start, const int* __restrict__ deg,
                           const int* __restrict__ csr_src,
                           const float* __restrict__ ss, const float* __restrict__ ds,
                           const float* __restrict__ H, float* __restrict__ OUT) {
    const int F   = 1 << LOGF;    // 32 or 64
    const int LPE = F / 4;        // lanes per edge: 8 or 16
    const int GRP = 64 / LPE;     // concurrent edges: 8 or 4
    int wid = (blockIdx.x * blockDim.x + threadIdx.x) >> 6;
    int lane = threadIdx.x & 63;
    if (wid >= NN) return;
    int start = row_start[wid];
    int dg = deg[wid];
    float dsv = ds[wid];

    // pass 1: per-lane alpha; cache first-64 edges in registers
    int   s_reg = 0;
    float alpha_reg = -1e30f;
    float m = -1e30f;
    if (lane < dg) {
        s_reg = csr_src[start + lane];
        alpha_reg = lrelu(ss[s_reg] + dsv);
        m = alpha_reg;
    }
    for (int i = lane + 64; i < dg; i += 64) {      // rare tail (deg>64)
        int s = csr_src[start + i];
        m = fmaxf(m, lrelu(ss[s] + dsv));
    }
    #pragma unroll
    for (int o = 32; o; o >>= 1) m = fmaxf(m, __shfl_xor(m, o, 64));

    // pass 2: exp-sum from cached alpha (no re-gather)
    float sum = (lane < dg) ? __expf(alpha_reg - m) : 0.0f;
    for (int i = lane + 64; i < dg; i += 64) {
        int s = csr_src[start + i];
        sum += __expf(lrelu(ss[s] + dsv) - m);
    }
    #pragma unroll
    for (int o = 32; o; o >>= 1) sum += __shfl_xor(sum, o, 64);
    float inv = 1.0f / (sum + SM_EPS);

    // pass 3: GRP edges in parallel; 4 features (float4) per lane.
    // Uniform round count: every lane executes every round, shfl always
    // sees all source lanes active; accumulate predicated on t < nfull.
    int g  = lane >> (LOGF - 2);        // lane / LPE  -> edge group
    int f4 = lane & (LPE - 1);          // float4 index within features
    float4 acc = make_float4(0.f, 0.f, 0.f, 0.f);
    int nfull = dg < 64 ? dg : 64;
    int rounds = (nfull + GRP - 1) / GRP;           // wave-uniform
    for (int k = 0; k < rounds; ++k) {
        int t = g + k * GRP;                        // <= 63 always
        int   s = __shfl(s_reg, t, 64);             // all lanes active here
        float a = __shfl(alpha_reg, t, 64);
        if (t < nfull) {
            float ev = __expf(a - m);
            const float4 hv = *(const float4*)&H[(size_t)s * F + f4 * 4];
            acc.x += ev * hv.x; acc.y += ev * hv.y;
            acc.z += ev * hv.z; acc.w += ev * hv.w;
        }
    }
    for (int t = 64 + g; t < dg; t += GRP) {        // rare tail, no shfl inside
        int s = csr_src[start + t];
        float ev = __expf(lrelu(ss[s] + dsv) - m);
        const float4 hv = *(const float4*)&H[(size_t)s * F + f4 * 4];
        acc.x += ev * hv.x; acc.y += ev * hv.y;
        acc.z += ev * hv.z; acc.w += ev * hv.w;
    }
    // combine edge groups (all lanes reconverged)
    #pragma unroll
    for (int o = LPE; o < 64; o <<= 1) {
        acc.x += __shfl_xor(acc.x, o, 64);
        acc.y += __shfl_xor(acc.y, o, 64);
        acc.z += __shfl_xor(acc.z, o, 64);
        acc.w += __shfl_xor(acc.w, o, 64);
    }
    if (lane < LPE) {
        acc.x *= inv; acc.y *= inv; acc.z *= inv; acc.w *= inv;
        *(float4*)&OUT[(size_t)wid * F + lane * 4] = acc;
    }
}

// ---------------- layer 2 projection + scores ----------------
__global__ void k5_h2(const float* __restrict__ OUT1,  // N x 32
                      const float* __restrict__ b1,
                      const float* __restrict__ W2,    // 32 x 64
                      const float* __restrict__ a2s, const float* __restrict__ a2d,
                      float* __restrict__ H2,
                      float* __restrict__ ss, float* __restrict__ ds) {
    __shared__ float w2s[32 * 64];
    __shared__ float b1s[32];
    int t = threadIdx.x;
    for (int i = t; i < 32 * 64; i += 256) w2s[i] = W2[i];
    if (t < 32) b1s[t] = b1[t];
    __syncthreads();
    int idx = blockIdx.x * 256 + t;
    int n = idx >> 6, f = idx & 63;
    if (n >= NN) return;
    float acc = 0.0f;
    #pragma unroll
    for (int k = 0; k < 32; ++k) {
        float xv = OUT1[n * 32 + k] + b1s[k];
        xv = xv > 0.0f ? xv : 0.0f;
        acc += xv * w2s[k * 64 + f];
    }
    H2[n * 64 + f] = acc;
    float vs = acc * a2s[f];
    float vd = acc * a2d[f];
    #pragma unroll
    for (int m = 32; m; m >>= 1) {
        vs += __shfl_xor(vs, m, 64);
        vd += __shfl_xor(vd, m, 64);
    }
    if (f == 0) { ss[n] = vs; ds[n] = vd; }
}

// ---------------- pool (segmented, low-contention) + fc ----------------
#define POOL_CHUNK 64
__global__ void k6_pool(const float* __restrict__ OUT2, const float* __restrict__ b2,
                        const int* __restrict__ batch,
                        float* __restrict__ pooled, float* __restrict__ cnts) {
    int wid = (blockIdx.x * blockDim.x + threadIdx.x) >> 6;
    int lane = threadIdx.x & 63;
    int n0 = wid * POOL_CHUNK;
    if (n0 >= NN) return;
    int n1 = n0 + POOL_CHUNK; if (n1 > NN) n1 = NN;
    float bv = b2[lane];
    int curg = batch[n0];
    float acc = 0.0f;
    int cnt = 0;
    for (int n = n0; n < n1; ++n) {
        int g = batch[n];                       // wave-uniform
        if (g != curg) {
            atomicAdd(&pooled[curg * 64 + lane], acc);
            if (lane == 0) atomicAdd(&cnts[curg], (float)cnt);
            acc = 0.0f; cnt = 0; curg = g;
        }
        float v = OUT2[(size_t)n * 64 + lane] + bv;
        acc += v > 0.0f ? v : 0.0f;
        ++cnt;
    }
    atomicAdd(&pooled[curg * 64 + lane], acc);
    if (lane == 0) atomicAdd(&cnts[curg], (float)cnt);
}

__global__ void k7_fc(const float* __restrict__ pooled, const float* __restrict__ cnts,
                      const float* __restrict__ fcW, const float* __restrict__ fcb,
                      float* __restrict__ out) {
    int g = threadIdx.x;
    if (g >= NG) return;
    float c = fmaxf(cnts[g], 1.0f);
    float o0 = fcb[0], o1 = fcb[1];
    for (int f = 0; f < 64; ++f) {
        float p = pooled[g * 64 + f] / c;
        o0 += p * fcW[f * 2 + 0];
        o1 += p * fcW[f * 2 + 1];
    }
    out[g * 2 + 0] = o0;
    out[g * 2 + 1] = o1;
}

extern "C" void kernel_launch(void* const* d_in, const int* in_sizes, int n_in,
                              void* d_out, int out_size, void* d_ws, size_t ws_size,
                              hipStream_t stream) {
    const float* x    = (const float*)d_in[0];
    const int*   ei   = (const int*)d_in[1];
    const int*   src  = ei;
    const int*   dst  = ei + NE;
    const int*   batch= (const int*)d_in[2];
    const float* W1   = (const float*)d_in[3];
    const float* a1s  = (const float*)d_in[4];
    const float* a1d  = (const float*)d_in[5];
    const float* b1   = (const float*)d_in[6];
    const float* W2   = (const float*)d_in[7];
    const float* a2s  = (const float*)d_in[8];
    const float* a2d  = (const float*)d_in[9];
    const float* b2   = (const float*)d_in[10];
    const float* fcW  = (const float*)d_in[11];
    const float* fcb  = (const float*)d_in[12];
    float* out = (float*)d_out;

    int* deg       = (int*)d_ws;            // NN
    int* row_start = deg + NN;              // NN
    int* cursor    = row_start + NN;        // NN
    int* bsum      = cursor + NN;           // 512
    int* csr_src   = bsum + 512;            // ET
    float* scoreS  = (float*)(csr_src + ET);// NN
    float* scoreD  = scoreS + NN;           // NN
    float* H       = scoreD + NN;           // NN*64  (16B-aligned)
    float* OUT     = H + (size_t)NN * 64;   // NN*64
    float* pooled  = OUT + (size_t)NN * 64; // NG*64
    float* cnts    = pooled + NG * 64;      // NG

    const int B = 256;
    int gridE = (ET + B - 1) / B;
    int gridW = (NN * 64 + B - 1) / B;      // wave-per-node kernels

    // ---- CSR build (shared by both layers) ----
    hipMemsetAsync(deg, 0, (size_t)NN * 4, stream);
    k_hist<<<gridE, B, 0, stream>>>(dst, deg);
    k_scan_a<<<NCHUNK, SCAN_B, 0, stream>>>(deg, bsum);
    k_scan_b<<<1, 512, 0, stream>>>(bsum);
    k_scan_c<<<NCHUNK, SCAN_B, 0, stream>>>(deg, bsum, row_start, cursor);
    k_scatter<<<gridE, B, 0, stream>>>(src, dst, cursor, csr_src);

    // ---- layer 1 (F=32) ----
    k1_h1_scores<<<(NN * 32 + B - 1) / B, B, 0, stream>>>(x, W1, a1s, a1d, H, scoreS, scoreD);
    k_gat_node<5><<<gridW, B, 0, stream>>>(row_start, deg, csr_src, scoreS, scoreD, H, OUT);

    // ---- layer 2 projection ----
    k5_h2<<<gridW, B, 0, stream>>>(OUT, b1, W2, a2s, a2d, H, scoreS, scoreD);

    // ---- layer 2 (F=64) ----
    k_gat_node<6><<<gridW, B, 0, stream>>>(row_start, deg, csr_src, scoreS, scoreD, H, OUT);

    // ---- pool + fc ----
    hipMemsetAsync(pooled, 0, (size_t)(NG * 64 + NG) * 4, stream);
    int gridP = ((NN + POOL_CHUNK - 1) / POOL_CHUNK * 64 + B - 1) / B;
    k6_pool<<<gridP, B, 0, stream>>>(OUT, b2, batch, pooled, cnts);
    k7_fc<<<1, B, 0, stream>>>(pooled, cnts, fcW, fcb, out);
}

// Round 6
// 364.302 us; speedup vs baseline: 3.5180x; 1.1306x over previous
//
#include <hip/hip_runtime.h>

#define NN 100000
#define NE 1600000
#define ET (NE + NN)      // logical edges incl. self-loops
#define NG 256
#define NEG_SLOPE 0.2f
#define SM_EPS 1e-16f

#define SCAN_B 256
#define NCHUNK ((NN + SCAN_B - 1) / SCAN_B)   // 391

// ---- bucketed CSR build params ----
#define NBUCK 32
#define BSHIFT 12                 // bucket = dst >> 12  (4096 nodes/bucket)
#define BSTRIDE 80000             // slots per bucket (mean 69.6K, +40 sigma)
#define EPB 2048                  // edges per block in bucket passes
#define NBLK ((ET + EPB - 1) / EPB)   // 831
#define XK 256                    // blocks per XCD in affine passes

__device__ __forceinline__ float lrelu(float x) { return x > 0.0f ? x : NEG_SLOPE * x; }

__device__ __forceinline__ void edge_sd(const int* __restrict__ src,
                                        const int* __restrict__ dst,
                                        int e, int& s, int& d) {
    if (e < NE) { s = src[e]; d = dst[e]; } else { s = e - NE; d = s; }
}

// ---------------- bucket pass A1: per-block per-bucket counts ----------------
__global__ void k_countA(const int* __restrict__ src, const int* __restrict__ dst,
                         int* __restrict__ bcnt) {
    __shared__ int cnt[NBUCK];
    int t = threadIdx.x, bid = blockIdx.x;
    if (t < NBUCK) cnt[t] = 0;
    __syncthreads();
    int e0 = bid * EPB;
    #pragma unroll
    for (int k = 0; k < EPB / 256; ++k) {
        int e = e0 + k * 256 + t;
        if (e < ET) {
            int s, d; edge_sd(src, dst, e, s, d);
            atomicAdd(&cnt[d >> BSHIFT], 1);
        }
    }
    __syncthreads();
    if (t < NBUCK) bcnt[t * NBLK + bid] = cnt[t];
}

// ---------------- A2: per-bucket exclusive prefix over blocks ----------------
// 2 blocks x 1024 threads; wave w scans row (blockIdx*16 + w) of bcnt in-place.
__global__ void k_scanblk(int* __restrict__ bcnt, int* __restrict__ gcnt) {
    int lane = threadIdx.x & 63;
    int row = blockIdx.x * 16 + (threadIdx.x >> 6);
    int running = 0;
    const int chunks = (NBLK + 63) / 64;
    for (int c = 0; c < chunks; ++c) {
        int i = c * 64 + lane;
        int v = (i < NBLK) ? bcnt[row * NBLK + i] : 0;
        int incl = v;
        #pragma unroll
        for (int o = 1; o < 64; o <<= 1) {
            int u = __shfl_up(incl, o, 64);
            if (lane >= o) incl += u;
        }
        if (i < NBLK) bcnt[row * NBLK + i] = row * BSTRIDE + running + (incl - v);
        running += __shfl(incl, 63, 64);
    }
    if (lane == 0) gcnt[row] = running;
}

// ---------------- A3: fill bucketed edge array (deterministic bases) ----------------
__global__ void k_fillA(const int* __restrict__ src, const int* __restrict__ dst,
                        const int* __restrict__ bbase, int2* __restrict__ bedge) {
    __shared__ int base[NBUCK];
    __shared__ int lcnt[NBUCK];
    int t = threadIdx.x, bid = blockIdx.x;
    if (t < NBUCK) { base[t] = bbase[t * NBLK + bid]; lcnt[t] = 0; }
    __syncthreads();
    int e0 = bid * EPB;
    #pragma unroll
    for (int k = 0; k < EPB / 256; ++k) {
        int e = e0 + k * 256 + t;
        if (e < ET) {
            int s, d; edge_sd(src, dst, e, s, d);
            int b = d >> BSHIFT;
            int rank = atomicAdd(&lcnt[b], 1);
            bedge[base[b] + rank] = make_int2(s, d);
        }
    }
}

// ---------------- XCD-affine histogram over bucketed edges ----------------
__global__ void k_hist_x(const int* __restrict__ gcnt, const int2* __restrict__ bedge,
                         int* __restrict__ deg) {
    int bid = blockIdx.x;
    int xcd = bid & 7;
    int j = bid >> 3;          // 0..XK-1
    int t = threadIdx.x;
    for (int b = xcd; b < NBUCK; b += 8) {
        int count = gcnt[b];
        const int2* eb = bedge + (size_t)b * BSTRIDE;
        for (int i = j * 256 + t; i < count; i += XK * 256)
            atomicAdd(&deg[eb[i].y], 1);
    }
}

// ---------------- XCD-affine scatter into CSR ----------------
__global__ void k_scatter_x(const int* __restrict__ gcnt, const int2* __restrict__ bedge,
                            int* __restrict__ cursor, int* __restrict__ csr_src) {
    int bid = blockIdx.x;
    int xcd = bid & 7;
    int j = bid >> 3;
    int t = threadIdx.x;
    for (int b = xcd; b < NBUCK; b += 8) {
        int count = gcnt[b];
        const int2* eb = bedge + (size_t)b * BSTRIDE;
        for (int i = j * 256 + t; i < count; i += XK * 256) {
            int2 ed = eb[i];
            int pos = atomicAdd(&cursor[ed.y], 1);
            csr_src[pos] = ed.x;
        }
    }
}

// ---------------- node-degree scan (row_start, cursor) ----------------
__global__ void k_scan_a(const int* __restrict__ deg, int* __restrict__ bsum) {
    __shared__ int sm[SCAN_B];
    int b = blockIdx.x, t = threadIdx.x;
    int i = b * SCAN_B + t;
    sm[t] = (i < NN) ? deg[i] : 0;
    __syncthreads();
    for (int s = SCAN_B / 2; s; s >>= 1) {
        if (t < s) sm[t] += sm[t + s];
        __syncthreads();
    }
    if (t == 0) bsum[b] = sm[0];
}

__global__ void k_scan_b(int* __restrict__ bsum) {   // 1 block, 512 threads
    __shared__ int sm[512];
    int t = threadIdx.x;
    sm[t] = (t < NCHUNK) ? bsum[t] : 0;
    __syncthreads();
    for (int off = 1; off < 512; off <<= 1) {
        int v = (t >= off) ? sm[t - off] : 0;
        __syncthreads();
        sm[t] += v;
        __syncthreads();
    }
    if (t < NCHUNK) bsum[t] = (t == 0) ? 0 : sm[t - 1];   // exclusive
}

__global__ void k_scan_c(const int* __restrict__ deg, const int* __restrict__ bsum,
                         int* __restrict__ row_start, int* __restrict__ cursor) {
    __shared__ int sm[SCAN_B];
    int b = blockIdx.x, t = threadIdx.x;
    int i = b * SCAN_B + t;
    int v = (i < NN) ? deg[i] : 0;
    sm[t] = v;
    __syncthreads();
    for (int off = 1; off < SCAN_B; off <<= 1) {
        int u = (t >= off) ? sm[t - off] : 0;
        __syncthreads();
        sm[t] += u;
        __syncthreads();
    }
    if (i < NN) {
        int excl = sm[t] - v + bsum[b];
        row_start[i] = excl;
        cursor[i] = excl;
    }
}

// ---------------- layer 1 projection + scores ----------------
__global__ void k1_h1_scores(const float* __restrict__ x,
                             const float* __restrict__ W1,
                             const float* __restrict__ a1s,
                             const float* __restrict__ a1d,
                             float* __restrict__ H,
                             float* __restrict__ ss,
                             float* __restrict__ ds) {
    int tid = blockIdx.x * blockDim.x + threadIdx.x;
    if (tid >= NN * 32) return;
    int n = tid >> 5, f = tid & 31;
    float h = x[n] * W1[f];
    H[tid] = h;
    float vs = h * a1s[f];
    float vd = h * a1d[f];
    #pragma unroll
    for (int m = 16; m; m >>= 1) {
        vs += __shfl_xor(vs, m, 32);
        vd += __shfl_xor(vd, m, 32);
    }
    if (f == 0) { ss[n] = vs; ds[n] = vd; }
}

// ---------------- fused per-node GAT layer (softmax + aggregate) ----------------
template<int LOGF>
__global__ void k_gat_node(const int* __restrict__ row_start, const int* __restrict__ deg,
                           const int* __restrict__ csr_src,
                           const float* __restrict__ ss, const float* __restrict__ ds,
                           const float* __restrict__ H, float* __restrict__ OUT) {
    const int F   = 1 << LOGF;    // 32 or 64
    const int LPE = F / 4;        // lanes per edge: 8 or 16
    const int GRP = 64 / LPE;     // concurrent edges: 8 or 4
    int wid = (blockIdx.x * blockDim.x + threadIdx.x) >> 6;
    int lane = threadIdx.x & 63;
    if (wid >= NN) return;
    int start = row_start[wid];
    int dg = deg[wid];
    float dsv = ds[wid];

    // pass 1: per-lane alpha; cache first-64 edges in registers
    int   s_reg = 0;
    float alpha_reg = -1e30f;
    float m = -1e30f;
    if (lane < dg) {
        s_reg = csr_src[start + lane];
        alpha_reg = lrelu(ss[s_reg] + dsv);
        m = alpha_reg;
    }
    for (int i = lane + 64; i < dg; i += 64) {      // rare tail (deg>64)
        int s = csr_src[start + i];
        m = fmaxf(m, lrelu(ss[s] + dsv));
    }
    #pragma unroll
    for (int o = 32; o; o >>= 1) m = fmaxf(m, __shfl_xor(m, o, 64));

    // pass 2: exp-sum from cached alpha
    float sum = (lane < dg) ? __expf(alpha_reg - m) : 0.0f;
    for (int i = lane + 64; i < dg; i += 64) {
        int s = csr_src[start + i];
        sum += __expf(lrelu(ss[s] + dsv) - m);
    }
    #pragma unroll
    for (int o = 32; o; o >>= 1) sum += __shfl_xor(sum, o, 64);
    float inv = 1.0f / (sum + SM_EPS);

    // pass 3: GRP edges in parallel; float4 of features per lane.
    // Uniform round count: shfl always executes with all 64 lanes active.
    int g  = lane >> (LOGF - 2);
    int f4 = lane & (LPE - 1);
    float4 acc = make_float4(0.f, 0.f, 0.f, 0.f);
    int nfull = dg < 64 ? dg : 64;
    int rounds = (nfull + GRP - 1) / GRP;           // wave-uniform
    for (int k = 0; k < rounds; ++k) {
        int t = g + k * GRP;                        // <= 63 always
        int   s = __shfl(s_reg, t, 64);
        float a = __shfl(alpha_reg, t, 64);
        if (t < nfull) {
            float ev = __expf(a - m);
            const float4 hv = *(const float4*)&H[(size_t)s * F + f4 * 4];
            acc.x += ev * hv.x; acc.y += ev * hv.y;
            acc.z += ev * hv.z; acc.w += ev * hv.w;
        }
    }
    for (int t = 64 + g; t < dg; t += GRP) {        // rare tail
        int s = csr_src[start + t];
        float ev = __expf(lrelu(ss[s] + dsv) - m);
        const float4 hv = *(const float4*)&H[(size_t)s * F + f4 * 4];
        acc.x += ev * hv.x; acc.y += ev * hv.y;
        acc.z += ev * hv.z; acc.w += ev * hv.w;
    }
    #pragma unroll
    for (int o = LPE; o < 64; o <<= 1) {
        acc.x += __shfl_xor(acc.x, o, 64);
        acc.y += __shfl_xor(acc.y, o, 64);
        acc.z += __shfl_xor(acc.z, o, 64);
        acc.w += __shfl_xor(acc.w, o, 64);
    }
    if (lane < LPE) {
        acc.x *= inv; acc.y *= inv; acc.z *= inv; acc.w *= inv;
        *(float4*)&OUT[(size_t)wid * F + lane * 4] = acc;
    }
}

// ---------------- layer 2 projection + scores ----------------
__global__ void k5_h2(const float* __restrict__ OUT1,  // N x 32
                      const float* __restrict__ b1,
                      const float* __restrict__ W2,    // 32 x 64
                      const float* __restrict__ a2s, const float* __restrict__ a2d,
                      float* __restrict__ H2,
                      float* __restrict__ ss, float* __restrict__ ds) {
    __shared__ float w2s[32 * 64];
    __shared__ float b1s[32];
    int t = threadIdx.x;
    for (int i = t; i < 32 * 64; i += 256) w2s[i] = W2[i];
    if (t < 32) b1s[t] = b1[t];
    __syncthreads();
    int idx = blockIdx.x * 256 + t;
    int n = idx >> 6, f = idx & 63;
    if (n >= NN) return;
    float acc = 0.0f;
    #pragma unroll
    for (int k = 0; k < 32; ++k) {
        float xv = OUT1[n * 32 + k] + b1s[k];
        xv = xv > 0.0f ? xv : 0.0f;
        acc += xv * w2s[k * 64 + f];
    }
    H2[n * 64 + f] = acc;
    float vs = acc * a2s[f];
    float vd = acc * a2d[f];
    #pragma unroll
    for (int m = 32; m; m >>= 1) {
        vs += __shfl_xor(vs, m, 64);
        vd += __shfl_xor(vd, m, 64);
    }
    if (f == 0) { ss[n] = vs; ds[n] = vd; }
}

// ---------------- pool (segmented, low-contention) + fc ----------------
#define POOL_CHUNK 64
__global__ void k6_pool(const float* __restrict__ OUT2, const float* __restrict__ b2,
                        const int* __restrict__ batch,
                        float* __restrict__ pooled, float* __restrict__ cnts) {
    int wid = (blockIdx.x * blockDim.x + threadIdx.x) >> 6;
    int lane = threadIdx.x & 63;
    int n0 = wid * POOL_CHUNK;
    if (n0 >= NN) return;
    int n1 = n0 + POOL_CHUNK; if (n1 > NN) n1 = NN;
    float bv = b2[lane];
    int curg = batch[n0];
    float acc = 0.0f;
    int cnt = 0;
    for (int n = n0; n < n1; ++n) {
        int g = batch[n];                       // wave-uniform
        if (g != curg) {
            atomicAdd(&pooled[curg * 64 + lane], acc);
            if (lane == 0) atomicAdd(&cnts[curg], (float)cnt);
            acc = 0.0f; cnt = 0; curg = g;
        }
        float v = OUT2[(size_t)n * 64 + lane] + bv;
        acc += v > 0.0f ? v : 0.0f;
        ++cnt;
    }
    atomicAdd(&pooled[curg * 64 + lane], acc);
    if (lane == 0) atomicAdd(&cnts[curg], (float)cnt);
}

__global__ void k7_fc(const float* __restrict__ pooled, const float* __restrict__ cnts,
                      const float* __restrict__ fcW, const float* __restrict__ fcb,
                      float* __restrict__ out) {
    int g = threadIdx.x;
    if (g >= NG) return;
    float c = fmaxf(cnts[g], 1.0f);
    float o0 = fcb[0], o1 = fcb[1];
    for (int f = 0; f < 64; ++f) {
        float p = pooled[g * 64 + f] / c;
        o0 += p * fcW[f * 2 + 0];
        o1 += p * fcW[f * 2 + 1];
    }
    out[g * 2 + 0] = o0;
    out[g * 2 + 1] = o1;
}

extern "C" void kernel_launch(void* const* d_in, const int* in_sizes, int n_in,
                              void* d_out, int out_size, void* d_ws, size_t ws_size,
                              hipStream_t stream) {
    const float* x    = (const float*)d_in[0];
    const int*   ei   = (const int*)d_in[1];
    const int*   src  = ei;
    const int*   dst  = ei + NE;
    const int*   batch= (const int*)d_in[2];
    const float* W1   = (const float*)d_in[3];
    const float* a1s  = (const float*)d_in[4];
    const float* a1d  = (const float*)d_in[5];
    const float* b1   = (const float*)d_in[6];
    const float* W2   = (const float*)d_in[7];
    const float* a2s  = (const float*)d_in[8];
    const float* a2d  = (const float*)d_in[9];
    const float* b2   = (const float*)d_in[10];
    const float* fcW  = (const float*)d_in[11];
    const float* fcb  = (const float*)d_in[12];
    float* out = (float*)d_out;

    int* deg       = (int*)d_ws;            // NN
    int* row_start = deg + NN;              // NN
    int* cursor    = row_start + NN;        // NN
    int* bsum      = cursor + NN;           // 512
    int* csr_src   = bsum + 512;            // ET
    float* scoreS  = (float*)(csr_src + ET);// NN
    float* scoreD  = scoreS + NN;           // NN
    float* H       = scoreD + NN;           // NN*64  (16B-aligned)
    float* OUT     = H + (size_t)NN * 64;   // NN*64
    float* pooled  = OUT + (size_t)NN * 64; // NG*64
    float* cnts    = pooled + NG * 64;      // NG
    int*   bcnt    = (int*)(cnts + NG);     // NBUCK*NBLK (prefix bases in-place)
    int*   gcnt    = bcnt + NBUCK * NBLK;   // NBUCK
    int2*  bedge   = (int2*)OUT;            // alias: NBUCK*BSTRIDE*8B = 20.5MB <= 25.6MB
                                            // (dead before gat_node<5> writes OUT)

    const int B = 256;
    int gridW = (NN * 64 + B - 1) / B;      // wave-per-node kernels

    // ---- bucketed CSR build ----
    hipMemsetAsync(deg, 0, (size_t)NN * 4, stream);
    k_countA<<<NBLK, B, 0, stream>>>(src, dst, bcnt);
    k_scanblk<<<2, 1024, 0, stream>>>(bcnt, gcnt);
    k_fillA<<<NBLK, B, 0, stream>>>(src, dst, bcnt, bedge);
    k_hist_x<<<8 * XK, B, 0, stream>>>(gcnt, bedge, deg);
    k_scan_a<<<NCHUNK, SCAN_B, 0, stream>>>(deg, bsum);
    k_scan_b<<<1, 512, 0, stream>>>(bsum);
    k_scan_c<<<NCHUNK, SCAN_B, 0, stream>>>(deg, bsum, row_start, cursor);
    k_scatter_x<<<8 * XK, B, 0, stream>>>(gcnt, bedge, cursor, csr_src);

    // ---- layer 1 (F=32) ----
    k1_h1_scores<<<(NN * 32 + B - 1) / B, B, 0, stream>>>(x, W1, a1s, a1d, H, scoreS, scoreD);
    k_gat_node<5><<<gridW, B, 0, stream>>>(row_start, deg, csr_src, scoreS, scoreD, H, OUT);

    // ---- layer 2 projection ----
    k5_h2<<<gridW, B, 0, stream>>>(OUT, b1, W2, a2s, a2d, H, scoreS, scoreD);

    // ---- layer 2 (F=64) ----
    k_gat_node<6><<<gridW, B, 0, stream>>>(row_start, deg, csr_src, scoreS, scoreD, H, OUT);

    // ---- pool + fc ----
    hipMemsetAsync(pooled, 0, (size_t)(NG * 64 + NG) * 4, stream);
    int gridP = ((NN + POOL_CHUNK - 1) / POOL_CHUNK * 64 + B - 1) / B;
    k6_pool<<<gridP, B, 0, stream>>>(OUT, b2, batch, pooled, cnts);
    k7_fc<<<1, B, 0, stream>>>(pooled, cnts, fcW, fcb, out);
}

// Round 7
// 252.242 us; speedup vs baseline: 5.0809x; 1.4443x over previous
//
#include <hip/hip_runtime.h>

#define NN 100000
#define NE 1600000
#define ET (NE + NN)      // logical edges incl. self-loops
#define NG 256
#define NEG_SLOPE 0.2f
#define SM_EPS 1e-16f

// ---- two-level bucketed CSR build ----
#define BSHIFT 7                       // bucket = dst >> 7 (128 nodes/bucket)
#define NBUCK ((NN + 127) / 128)       // 782
#define EPB 8192                       // edges per block in count/fill passes
#define NBLK ((ET + EPB - 1) / EPB)    // 208
#define MAXB 5120                      // LDS staging cap (max bucket ~2400)

__device__ __forceinline__ float lrelu(float x) { return x > 0.0f ? x : NEG_SLOPE * x; }

__device__ __forceinline__ void edge_sd(const int* __restrict__ src,
                                        const int* __restrict__ dst,
                                        int e, int& s, int& d) {
    if (e < NE) { s = src[e]; d = dst[e]; } else { s = e - NE; d = s; }
}

// ---- A1: per-block per-bucket counts ----
__global__ void k_countA(const int* __restrict__ src, const int* __restrict__ dst,
                         int* __restrict__ bcnt) {
    __shared__ int cnt[NBUCK];
    int t = threadIdx.x, bid = blockIdx.x;
    for (int i = t; i < NBUCK; i += 256) cnt[i] = 0;
    __syncthreads();
    int e0 = bid * EPB;
    #pragma unroll
    for (int k = 0; k < EPB / 256; ++k) {
        int e = e0 + k * 256 + t;
        if (e < ET) {
            int s, d; edge_sd(src, dst, e, s, d);
            atomicAdd(&cnt[d >> BSHIFT], 1);
        }
    }
    __syncthreads();
    for (int i = t; i < NBUCK; i += 256) bcnt[i * NBLK + bid] = cnt[i];
}

// ---- A2a: per-bucket exclusive prefix over blocks (one block/bucket-row) ----
__global__ void k_scanrow(int* __restrict__ bcnt, int* __restrict__ gcnt) {
    int row = blockIdx.x, lane = threadIdx.x;   // 64 threads
    int running = 0;
    const int chunks = (NBLK + 63) / 64;
    for (int c = 0; c < chunks; ++c) {
        int i = c * 64 + lane;
        int v = (i < NBLK) ? bcnt[row * NBLK + i] : 0;
        int incl = v;
        #pragma unroll
        for (int o = 1; o < 64; o <<= 1) {
            int u = __shfl_up(incl, o, 64);
            if (lane >= o) incl += u;
        }
        if (i < NBLK) bcnt[row * NBLK + i] = running + (incl - v);
        running += __shfl(incl, 63, 64);
    }
    if (lane == 0) gcnt[row] = running;
}

// ---- A2b: exclusive scan of bucket totals -> compact bucket bases ----
__global__ void k_gscan(const int* __restrict__ gcnt, int* __restrict__ gbase) {
    __shared__ int sm[1024];
    int t = threadIdx.x;
    int v = (t < NBUCK) ? gcnt[t] : 0;
    sm[t] = v;
    __syncthreads();
    for (int off = 1; off < 1024; off <<= 1) {
        int u = (t >= off) ? sm[t - off] : 0;
        __syncthreads();
        sm[t] += u;
        __syncthreads();
    }
    if (t < NBUCK) gbase[t] = sm[t] - v;
}

// ---- A3: fill compact bucket-major edge array (deterministic bases) ----
__global__ void k_fillA(const int* __restrict__ src, const int* __restrict__ dst,
                        const int* __restrict__ bcnt, const int* __restrict__ gbase,
                        int2* __restrict__ bedge) {
    __shared__ int base[NBUCK];
    __shared__ int lcnt[NBUCK];
    int t = threadIdx.x, bid = blockIdx.x;
    for (int i = t; i < NBUCK; i += 256) {
        base[i] = gbase[i] + bcnt[i * NBLK + bid];
        lcnt[i] = 0;
    }
    __syncthreads();
    int e0 = bid * EPB;
    #pragma unroll
    for (int k = 0; k < EPB / 256; ++k) {
        int e = e0 + k * 256 + t;
        if (e < ET) {
            int s, d; edge_sd(src, dst, e, s, d);
            int b = d >> BSHIFT;
            int rank = atomicAdd(&lcnt[b], 1);
            bedge[base[b] + rank] = make_int2(s, d);
        }
    }
}

// ---- B: per-bucket LDS counting sort -> coalesced CSR + deg + row_start ----
__global__ void k_sortB(const int* __restrict__ gcnt, const int* __restrict__ gbase,
                        const int2* __restrict__ bedge,
                        int* __restrict__ csr_src, int* __restrict__ deg,
                        int* __restrict__ row_start) {
    __shared__ int lcnt[128], lstart[128], lcur[128];
    __shared__ int lout[MAXB];
    int b = blockIdx.x, t = threadIdx.x;        // 256 threads
    int cnt = gcnt[b];
    int base = gbase[b];
    const int2* eb = bedge + base;
    if (t < 128) lcnt[t] = 0;
    __syncthreads();
    for (int i = t; i < cnt; i += 256)
        atomicAdd(&lcnt[eb[i].y & 127], 1);
    __syncthreads();
    if (t < 128) lstart[t] = lcnt[t];
    __syncthreads();
    for (int off = 1; off < 128; off <<= 1) {
        int v = (t >= off && t < 128) ? lstart[t - off] : 0;
        __syncthreads();
        if (t < 128) lstart[t] += v;
        __syncthreads();
    }
    if (t < 128) {
        lstart[t] -= lcnt[t];          // exclusive
        lcur[t] = lstart[t];
    }
    __syncthreads();
    for (int i = t; i < cnt; i += 256) {
        int2 ed = eb[i];
        int pos = atomicAdd(&lcur[ed.y & 127], 1);
        lout[pos] = ed.x;
    }
    __syncthreads();
    for (int i = t; i < cnt; i += 256)
        csr_src[base + i] = lout[i];
    int n = (b << BSHIFT) + t;
    if (t < 128 && n < NN) {
        deg[n] = lcnt[t];
        row_start[n] = base + lstart[t];
    }
}

// ---------------- layer 1 projection + scores ----------------
__global__ void k1_h1_scores(const float* __restrict__ x,
                             const float* __restrict__ W1,
                             const float* __restrict__ a1s,
                             const float* __restrict__ a1d,
                             float* __restrict__ H,
                             float* __restrict__ ss,
                             float* __restrict__ ds) {
    int tid = blockIdx.x * blockDim.x + threadIdx.x;
    if (tid >= NN * 32) return;
    int n = tid >> 5, f = tid & 31;
    float h = x[n] * W1[f];
    H[tid] = h;
    float vs = h * a1s[f];
    float vd = h * a1d[f];
    #pragma unroll
    for (int m = 16; m; m >>= 1) {
        vs += __shfl_xor(vs, m, 32);
        vd += __shfl_xor(vd, m, 32);
    }
    if (f == 0) { ss[n] = vs; ds[n] = vd; }
}

// ---------------- fused per-node GAT layer (softmax + aggregate) ----------------
template<int LOGF>
__global__ void k_gat_node(const int* __restrict__ row_start, const int* __restrict__ deg,
                           const int* __restrict__ csr_src,
                           const float* __restrict__ ss, const float* __restrict__ ds,
                           const float* __restrict__ H, float* __restrict__ OUT) {
    const int F   = 1 << LOGF;    // 32 or 64
    const int LPE = F / 4;        // lanes per edge: 8 or 16
    const int GRP = 64 / LPE;     // concurrent edges: 8 or 4
    int wid = (blockIdx.x * blockDim.x + threadIdx.x) >> 6;
    int lane = threadIdx.x & 63;
    if (wid >= NN) return;
    int start = row_start[wid];
    int dg = deg[wid];
    float dsv = ds[wid];

    // pass 1: per-lane alpha; cache first-64 edges in registers
    int   s_reg = 0;
    float alpha_reg = -1e30f;
    float m = -1e30f;
    if (lane < dg) {
        s_reg = csr_src[start + lane];
        alpha_reg = lrelu(ss[s_reg] + dsv);
        m = alpha_reg;
    }
    for (int i = lane + 64; i < dg; i += 64) {      // rare tail (deg>64)
        int s = csr_src[start + i];
        m = fmaxf(m, lrelu(ss[s] + dsv));
    }
    #pragma unroll
    for (int o = 32; o; o >>= 1) m = fmaxf(m, __shfl_xor(m, o, 64));

    // pass 2: exp-sum from cached alpha
    float sum = (lane < dg) ? __expf(alpha_reg - m) : 0.0f;
    for (int i = lane + 64; i < dg; i += 64) {
        int s = csr_src[start + i];
        sum += __expf(lrelu(ss[s] + dsv) - m);
    }
    #pragma unroll
    for (int o = 32; o; o >>= 1) sum += __shfl_xor(sum, o, 64);
    float inv = 1.0f / (sum + SM_EPS);

    // pass 3: GRP edges in parallel; float4 of features per lane.
    // Uniform round count: shfl always executes with all 64 lanes active.
    int g  = lane >> (LOGF - 2);
    int f4 = lane & (LPE - 1);
    float4 acc = make_float4(0.f, 0.f, 0.f, 0.f);
    int nfull = dg < 64 ? dg : 64;
    int rounds = (nfull + GRP - 1) / GRP;           // wave-uniform
    for (int k = 0; k < rounds; ++k) {
        int t = g + k * GRP;                        // <= 63 always
        int   s = __shfl(s_reg, t, 64);
        float a = __shfl(alpha_reg, t, 64);
        if (t < nfull) {
            float ev = __expf(a - m);
            const float4 hv = *(const float4*)&H[(size_t)s * F + f4 * 4];
            acc.x += ev * hv.x; acc.y += ev * hv.y;
            acc.z += ev * hv.z; acc.w += ev * hv.w;
        }
    }
    for (int t = 64 + g; t < dg; t += GRP) {        // rare tail
        int s = csr_src[start + t];
        float ev = __expf(lrelu(ss[s] + dsv) - m);
        const float4 hv = *(const float4*)&H[(size_t)s * F + f4 * 4];
        acc.x += ev * hv.x; acc.y += ev * hv.y;
        acc.z += ev * hv.z; acc.w += ev * hv.w;
    }
    #pragma unroll
    for (int o = LPE; o < 64; o <<= 1) {
        acc.x += __shfl_xor(acc.x, o, 64);
        acc.y += __shfl_xor(acc.y, o, 64);
        acc.z += __shfl_xor(acc.z, o, 64);
        acc.w += __shfl_xor(acc.w, o, 64);
    }
    if (lane < LPE) {
        acc.x *= inv; acc.y *= inv; acc.z *= inv; acc.w *= inv;
        *(float4*)&OUT[(size_t)wid * F + lane * 4] = acc;
    }
}

// ---------------- layer 2 projection + scores ----------------
__global__ void k5_h2(const float* __restrict__ OUT1,  // N x 32
                      const float* __restrict__ b1,
                      const float* __restrict__ W2,    // 32 x 64
                      const float* __restrict__ a2s, const float* __restrict__ a2d,
                      float* __restrict__ H2,
                      float* __restrict__ ss, float* __restrict__ ds) {
    __shared__ float w2s[32 * 64];
    __shared__ float b1s[32];
    int t = threadIdx.x;
    for (int i = t; i < 32 * 64; i += 256) w2s[i] = W2[i];
    if (t < 32) b1s[t] = b1[t];
    __syncthreads();
    int idx = blockIdx.x * 256 + t;
    int n = idx >> 6, f = idx & 63;
    if (n >= NN) return;
    float acc = 0.0f;
    #pragma unroll
    for (int k = 0; k < 32; ++k) {
        float xv = OUT1[n * 32 + k] + b1s[k];
        xv = xv > 0.0f ? xv : 0.0f;
        acc += xv * w2s[k * 64 + f];
    }
    H2[n * 64 + f] = acc;
    float vs = acc * a2s[f];
    float vd = acc * a2d[f];
    #pragma unroll
    for (int m = 32; m; m >>= 1) {
        vs += __shfl_xor(vs, m, 64);
        vd += __shfl_xor(vd, m, 64);
    }
    if (f == 0) { ss[n] = vs; ds[n] = vd; }
}

// ---------------- pool (segmented, low-contention) + fc ----------------
#define POOL_CHUNK 64
__global__ void k6_pool(const float* __restrict__ OUT2, const float* __restrict__ b2,
                        const int* __restrict__ batch,
                        float* __restrict__ pooled, float* __restrict__ cnts) {
    int wid = (blockIdx.x * blockDim.x + threadIdx.x) >> 6;
    int lane = threadIdx.x & 63;
    int n0 = wid * POOL_CHUNK;
    if (n0 >= NN) return;
    int n1 = n0 + POOL_CHUNK; if (n1 > NN) n1 = NN;
    float bv = b2[lane];
    int curg = batch[n0];
    float acc = 0.0f;
    int cnt = 0;
    for (int n = n0; n < n1; ++n) {
        int g = batch[n];                       // wave-uniform
        if (g != curg) {
            atomicAdd(&pooled[curg * 64 + lane], acc);
            if (lane == 0) atomicAdd(&cnts[curg], (float)cnt);
            acc = 0.0f; cnt = 0; curg = g;
        }
        float v = OUT2[(size_t)n * 64 + lane] + bv;
        acc += v > 0.0f ? v : 0.0f;
        ++cnt;
    }
    atomicAdd(&pooled[curg * 64 + lane], acc);
    if (lane == 0) atomicAdd(&cnts[curg], (float)cnt);
}

__global__ void k7_fc(const float* __restrict__ pooled, const float* __restrict__ cnts,
                      const float* __restrict__ fcW, const float* __restrict__ fcb,
                      float* __restrict__ out) {
    int g = threadIdx.x;
    if (g >= NG) return;
    float c = fmaxf(cnts[g], 1.0f);
    float o0 = fcb[0], o1 = fcb[1];
    for (int f = 0; f < 64; ++f) {
        float p = pooled[g * 64 + f] / c;
        o0 += p * fcW[f * 2 + 0];
        o1 += p * fcW[f * 2 + 1];
    }
    out[g * 2 + 0] = o0;
    out[g * 2 + 1] = o1;
}

extern "C" void kernel_launch(void* const* d_in, const int* in_sizes, int n_in,
                              void* d_out, int out_size, void* d_ws, size_t ws_size,
                              hipStream_t stream) {
    const float* x    = (const float*)d_in[0];
    const int*   ei   = (const int*)d_in[1];
    const int*   src  = ei;
    const int*   dst  = ei + NE;
    const int*   batch= (const int*)d_in[2];
    const float* W1   = (const float*)d_in[3];
    const float* a1s  = (const float*)d_in[4];
    const float* a1d  = (const float*)d_in[5];
    const float* b1   = (const float*)d_in[6];
    const float* W2   = (const float*)d_in[7];
    const float* a2s  = (const float*)d_in[8];
    const float* a2d  = (const float*)d_in[9];
    const float* b2   = (const float*)d_in[10];
    const float* fcW  = (const float*)d_in[11];
    const float* fcb  = (const float*)d_in[12];
    float* out = (float*)d_out;

    int* deg       = (int*)d_ws;            // NN
    int* row_start = deg + NN;              // NN
    int* csr_src   = row_start + NN;        // ET
    float* scoreS  = (float*)(csr_src + ET);// NN
    float* scoreD  = scoreS + NN;           // NN
    float* H       = scoreD + NN;           // NN*64 (16B-aligned)
    float* OUT     = H + (size_t)NN * 64;   // NN*64
    float* pooled  = OUT + (size_t)NN * 64; // NG*64
    float* cnts    = pooled + NG * 64;      // NG
    int*   bcnt    = (int*)(cnts + NG);     // NBUCK*NBLK
    int*   gcnt    = bcnt + NBUCK * NBLK;   // NBUCK
    int*   gbase   = gcnt + NBUCK;          // NBUCK
    int2*  bedge   = (int2*)H;              // alias: ET*8B = 13.6MB <= 25.6MB (dead before k1 writes H)

    const int B = 256;
    int gridW = (NN * 64 + B - 1) / B;      // wave-per-node kernels

    // ---- CSR build: two-level LDS counting sort, zero global atomics ----
    k_countA<<<NBLK, B, 0, stream>>>(src, dst, bcnt);
    k_scanrow<<<NBUCK, 64, 0, stream>>>(bcnt, gcnt);
    k_gscan<<<1, 1024, 0, stream>>>(gcnt, gbase);
    k_fillA<<<NBLK, B, 0, stream>>>(src, dst, bcnt, gbase, bedge);
    k_sortB<<<NBUCK, B, 0, stream>>>(gcnt, gbase, bedge, csr_src, deg, row_start);

    // ---- layer 1 (F=32) ----
    k1_h1_scores<<<(NN * 32 + B - 1) / B, B, 0, stream>>>(x, W1, a1s, a1d, H, scoreS, scoreD);
    k_gat_node<5><<<gridW, B, 0, stream>>>(row_start, deg, csr_src, scoreS, scoreD, H, OUT);

    // ---- layer 2 projection ----
    k5_h2<<<gridW, B, 0, stream>>>(OUT, b1, W2, a2s, a2d, H, scoreS, scoreD);

    // ---- layer 2 (F=64) ----
    k_gat_node<6><<<gridW, B, 0, stream>>>(row_start, deg, csr_src, scoreS, scoreD, H, OUT);

    // ---- pool + fc ----
    hipMemsetAsync(pooled, 0, (size_t)(NG * 64 + NG) * 4, stream);
    int gridP = ((NN + POOL_CHUNK - 1) / POOL_CHUNK * 64 + B - 1) / B;
    k6_pool<<<gridP, B, 0, stream>>>(OUT, b2, batch, pooled, cnts);
    k7_fc<<<1, B, 0, stream>>>(pooled, cnts, fcW, fcb, out);
}

// Round 8
// 211.784 us; speedup vs baseline: 6.0516x; 1.1910x over previous
//
#include <hip/hip_runtime.h>

#define NN 100000
#define NE 1600000
#define ET (NE + NN)      // logical edges incl. self-loops
#define NG 256
#define NEG_SLOPE 0.2f
#define SM_EPS 1e-16f

// ---- two-level bucketed CSR build ----
#define BSHIFT 7                       // bucket = dst >> 7 (128 nodes/bucket)
#define NBUCK ((NN + 127) / 128)       // 782
#define EPB 8192                       // edges per block in count/fill passes
#define NBLK ((ET + EPB - 1) / EPB)    // 208
#define MAXB 5120                      // LDS staging cap (max bucket ~2400)

typedef _Float16 half8 __attribute__((ext_vector_type(8)));

__device__ __forceinline__ float lrelu(float x) { return x > 0.0f ? x : NEG_SLOPE * x; }

__device__ __forceinline__ void edge_sd(const int* __restrict__ src,
                                        const int* __restrict__ dst,
                                        int e, int& s, int& d) {
    if (e < NE) { s = src[e]; d = dst[e]; } else { s = e - NE; d = s; }
}

// ---- A1: per-block per-bucket counts ----
__global__ void k_countA(const int* __restrict__ src, const int* __restrict__ dst,
                         int* __restrict__ bcnt) {
    __shared__ int cnt[NBUCK];
    int t = threadIdx.x, bid = blockIdx.x;
    for (int i = t; i < NBUCK; i += 256) cnt[i] = 0;
    __syncthreads();
    int e0 = bid * EPB;
    #pragma unroll
    for (int k = 0; k < EPB / 256; ++k) {
        int e = e0 + k * 256 + t;
        if (e < ET) {
            int s, d; edge_sd(src, dst, e, s, d);
            atomicAdd(&cnt[d >> BSHIFT], 1);
        }
    }
    __syncthreads();
    for (int i = t; i < NBUCK; i += 256) bcnt[i * NBLK + bid] = cnt[i];
}

// ---- A2a: per-bucket exclusive prefix over blocks ----
__global__ void k_scanrow(int* __restrict__ bcnt, int* __restrict__ gcnt) {
    int row = blockIdx.x, lane = threadIdx.x;   // 64 threads
    int running = 0;
    const int chunks = (NBLK + 63) / 64;
    for (int c = 0; c < chunks; ++c) {
        int i = c * 64 + lane;
        int v = (i < NBLK) ? bcnt[row * NBLK + i] : 0;
        int incl = v;
        #pragma unroll
        for (int o = 1; o < 64; o <<= 1) {
            int u = __shfl_up(incl, o, 64);
            if (lane >= o) incl += u;
        }
        if (i < NBLK) bcnt[row * NBLK + i] = running + (incl - v);
        running += __shfl(incl, 63, 64);
    }
    if (lane == 0) gcnt[row] = running;
}

// ---- A2b: exclusive scan of bucket totals ----
__global__ void k_gscan(const int* __restrict__ gcnt, int* __restrict__ gbase) {
    __shared__ int sm[1024];
    int t = threadIdx.x;
    int v = (t < NBUCK) ? gcnt[t] : 0;
    sm[t] = v;
    __syncthreads();
    for (int off = 1; off < 1024; off <<= 1) {
        int u = (t >= off) ? sm[t - off] : 0;
        __syncthreads();
        sm[t] += u;
        __syncthreads();
    }
    if (t < NBUCK) gbase[t] = sm[t] - v;
}

// ---- A3: fill compact bucket-major edge array ----
__global__ void k_fillA(const int* __restrict__ src, const int* __restrict__ dst,
                        const int* __restrict__ bcnt, const int* __restrict__ gbase,
                        int2* __restrict__ bedge) {
    __shared__ int base[NBUCK];
    __shared__ int lcnt[NBUCK];
    int t = threadIdx.x, bid = blockIdx.x;
    for (int i = t; i < NBUCK; i += 256) {
        base[i] = gbase[i] + bcnt[i * NBLK + bid];
        lcnt[i] = 0;
    }
    __syncthreads();
    int e0 = bid * EPB;
    #pragma unroll
    for (int k = 0; k < EPB / 256; ++k) {
        int e = e0 + k * 256 + t;
        if (e < ET) {
            int s, d; edge_sd(src, dst, e, s, d);
            int b = d >> BSHIFT;
            int rank = atomicAdd(&lcnt[b], 1);
            bedge[base[b] + rank] = make_int2(s, d);
        }
    }
}

// ---- B: per-bucket LDS counting sort -> coalesced CSR + deg + row_start ----
__global__ void k_sortB(const int* __restrict__ gcnt, const int* __restrict__ gbase,
                        const int2* __restrict__ bedge,
                        int* __restrict__ csr_src, int* __restrict__ deg,
                        int* __restrict__ row_start) {
    __shared__ int lcnt[128], lstart[128], lcur[128];
    __shared__ int lout[MAXB];
    int b = blockIdx.x, t = threadIdx.x;        // 256 threads
    int cnt = gcnt[b];
    int base = gbase[b];
    const int2* eb = bedge + base;
    if (t < 128) lcnt[t] = 0;
    __syncthreads();
    for (int i = t; i < cnt; i += 256)
        atomicAdd(&lcnt[eb[i].y & 127], 1);
    __syncthreads();
    if (t < 128) lstart[t] = lcnt[t];
    __syncthreads();
    for (int off = 1; off < 128; off <<= 1) {
        int v = (t >= off && t < 128) ? lstart[t - off] : 0;
        __syncthreads();
        if (t < 128) lstart[t] += v;
        __syncthreads();
    }
    if (t < 128) {
        lstart[t] -= lcnt[t];          // exclusive
        lcur[t] = lstart[t];
    }
    __syncthreads();
    for (int i = t; i < cnt; i += 256) {
        int2 ed = eb[i];
        int pos = atomicAdd(&lcur[ed.y & 127], 1);
        lout[pos] = ed.x;
    }
    __syncthreads();
    for (int i = t; i < cnt; i += 256)
        csr_src[base + i] = lout[i];
    int n = (b << BSHIFT) + t;
    if (t < 128 && n < NN) {
        deg[n] = lcnt[t];
        row_start[n] = base + lstart[t];
    }
}

// ---- layer-1 folded coefficients: c1s = W1·a1s, c1d = W1·a1d ----
__global__ void k_c1(const float* __restrict__ W1, const float* __restrict__ a1s,
                     const float* __restrict__ a1d, float2* __restrict__ c12) {
    int t = threadIdx.x;  // 64
    float w  = (t < 32) ? W1[t] : 0.0f;
    float vs = (t < 32) ? w * a1s[t] : 0.0f;
    float vd = (t < 32) ? w * a1d[t] : 0.0f;
    #pragma unroll
    for (int o = 32; o; o >>= 1) {
        vs += __shfl_xor(vs, o, 64);
        vd += __shfl_xor(vd, o, 64);
    }
    if (t == 0) *c12 = make_float2(vs, vd);
}

// ---- layer 1: scalar GAT (rank-1 structure), one wave per node ----
// alpha_e = lrelu(c1s*x[s] + c1d*x[d]);  Y[d] = softmax-weighted sum of x[s]
__global__ void k_gat1(const int* __restrict__ row_start, const int* __restrict__ deg,
                       const int* __restrict__ csr_src, const float* __restrict__ x,
                       const float2* __restrict__ c12, float* __restrict__ Y) {
    int wid = (blockIdx.x * blockDim.x + threadIdx.x) >> 6;
    int lane = threadIdx.x & 63;
    if (wid >= NN) return;
    float2 c = *c12;                 // wave-uniform
    float xd = x[wid];
    int start = row_start[wid];
    int dg = deg[wid];

    float xs_reg = 0.0f, alpha_reg = -1e30f, m = -1e30f;
    if (lane < dg) {
        int s = csr_src[start + lane];
        xs_reg = x[s];
        alpha_reg = lrelu(c.x * xs_reg + c.y * xd);
        m = alpha_reg;
    }
    for (int i = lane + 64; i < dg; i += 64) {      // rare tail
        float xs = x[csr_src[start + i]];
        m = fmaxf(m, lrelu(c.x * xs + c.y * xd));
    }
    #pragma unroll
    for (int o = 32; o; o >>= 1) m = fmaxf(m, __shfl_xor(m, o, 64));

    float ev = (lane < dg) ? __expf(alpha_reg - m) : 0.0f;
    float sum = ev, wy = ev * xs_reg;
    for (int i = lane + 64; i < dg; i += 64) {      // rare tail
        float xs = x[csr_src[start + i]];
        float e2 = __expf(lrelu(c.x * xs + c.y * xd) - m);
        sum += e2; wy += e2 * xs;
    }
    #pragma unroll
    for (int o = 32; o; o >>= 1) {
        sum += __shfl_xor(sum, o, 64);
        wy  += __shfl_xor(wy, o, 64);
    }
    if (lane == 0) Y[wid] = wy / (sum + SM_EPS);
}

// ---- layer 2 projection from scalar Y: x2 = relu(Y*W1+b1); H2 = x2@W2 (fp16) ----
__global__ void k5_h2(const float* __restrict__ Y,
                      const float* __restrict__ W1, const float* __restrict__ b1,
                      const float* __restrict__ W2,    // 32 x 64
                      const float* __restrict__ a2s, const float* __restrict__ a2d,
                      half8* __restrict__ H2h,
                      float* __restrict__ ss, float* __restrict__ ds) {
    __shared__ float w2s[32 * 64];
    __shared__ float w1s[32], b1s[32];
    int t = threadIdx.x;
    for (int i = t; i < 32 * 64; i += 256) w2s[i] = W2[i];
    if (t < 32) { w1s[t] = W1[t]; b1s[t] = b1[t]; }
    __syncthreads();
    int idx = blockIdx.x * 256 + t;
    int n = idx >> 6, f = idx & 63;
    if (n >= NN) return;
    float y = Y[n];
    float acc = 0.0f;
    #pragma unroll
    for (int k = 0; k < 32; ++k) {
        float xv = y * w1s[k] + b1s[k];
        xv = xv > 0.0f ? xv : 0.0f;
        acc += xv * w2s[k * 64 + f];
    }
    ((_Float16*)H2h)[(size_t)n * 64 + f] = (_Float16)acc;   // 2B coalesced
    float vs = acc * a2s[f];
    float vd = acc * a2d[f];
    #pragma unroll
    for (int m = 32; m; m >>= 1) {
        vs += __shfl_xor(vs, m, 64);
        vd += __shfl_xor(vd, m, 64);
    }
    if (f == 0) { ss[n] = vs; ds[n] = vd; }
}

// ---- layer 2 GAT: fp16 gather, 8 edges concurrent, 8 features/lane ----
__global__ void k_gat2(const int* __restrict__ row_start, const int* __restrict__ deg,
                       const int* __restrict__ csr_src,
                       const float* __restrict__ ss, const float* __restrict__ ds,
                       const half8* __restrict__ H2h, float* __restrict__ OUT) {
    int wid = (blockIdx.x * blockDim.x + threadIdx.x) >> 6;
    int lane = threadIdx.x & 63;
    if (wid >= NN) return;
    int start = row_start[wid];
    int dg = deg[wid];
    float dsv = ds[wid];

    int   s_reg = 0;
    float alpha_reg = -1e30f, m = -1e30f;
    if (lane < dg) {
        s_reg = csr_src[start + lane];
        alpha_reg = lrelu(ss[s_reg] + dsv);
        m = alpha_reg;
    }
    for (int i = lane + 64; i < dg; i += 64) {
        int s = csr_src[start + i];
        m = fmaxf(m, lrelu(ss[s] + dsv));
    }
    #pragma unroll
    for (int o = 32; o; o >>= 1) m = fmaxf(m, __shfl_xor(m, o, 64));

    float sum = (lane < dg) ? __expf(alpha_reg - m) : 0.0f;
    for (int i = lane + 64; i < dg; i += 64) {
        int s = csr_src[start + i];
        sum += __expf(lrelu(ss[s] + dsv) - m);
    }
    #pragma unroll
    for (int o = 32; o; o >>= 1) sum += __shfl_xor(sum, o, 64);
    float inv = 1.0f / (sum + SM_EPS);

    // 8 edge-groups x 8 features(half8)/lane; uniform rounds for shfl safety
    int g  = lane >> 3;
    int f8 = lane & 7;
    float acc[8] = {0, 0, 0, 0, 0, 0, 0, 0};
    int nfull = dg < 64 ? dg : 64;
    int rounds = (nfull + 7) / 8;                   // wave-uniform
    for (int k = 0; k < rounds; ++k) {
        int t = g + k * 8;                          // <= 63 always
        int   s = __shfl(s_reg, t, 64);
        float a = __shfl(alpha_reg, t, 64);
        if (t < nfull) {
            float ev = __expf(a - m);
            half8 hv = H2h[(size_t)s * 8 + f8];
            #pragma unroll
            for (int j = 0; j < 8; ++j) acc[j] += ev * (float)hv[j];
        }
    }
    for (int t = 64 + g; t < dg; t += 8) {          // rare tail
        int s = csr_src[start + t];
        float ev = __expf(lrelu(ss[s] + dsv) - m);
        half8 hv = H2h[(size_t)s * 8 + f8];
        #pragma unroll
        for (int j = 0; j < 8; ++j) acc[j] += ev * (float)hv[j];
    }
    #pragma unroll
    for (int o = 8; o < 64; o <<= 1)
        #pragma unroll
        for (int j = 0; j < 8; ++j) acc[j] += __shfl_xor(acc[j], o, 64);
    if (lane < 8) {
        float4* dst = (float4*)&OUT[(size_t)wid * 64 + lane * 8];
        dst[0] = make_float4(acc[0] * inv, acc[1] * inv, acc[2] * inv, acc[3] * inv);
        dst[1] = make_float4(acc[4] * inv, acc[5] * inv, acc[6] * inv, acc[7] * inv);
    }
}

// ---- pool (segmented, low-contention) + fc ----
#define POOL_CHUNK 64
__global__ void k6_pool(const float* __restrict__ OUT2, const float* __restrict__ b2,
                        const int* __restrict__ batch,
                        float* __restrict__ pooled, float* __restrict__ cnts) {
    int wid = (blockIdx.x * blockDim.x + threadIdx.x) >> 6;
    int lane = threadIdx.x & 63;
    int n0 = wid * POOL_CHUNK;
    if (n0 >= NN) return;
    int n1 = n0 + POOL_CHUNK; if (n1 > NN) n1 = NN;
    float bv = b2[lane];
    int curg = batch[n0];
    float acc = 0.0f;
    int cnt = 0;
    for (int n = n0; n < n1; ++n) {
        int g = batch[n];                       // wave-uniform
        if (g != curg) {
            atomicAdd(&pooled[curg * 64 + lane], acc);
            if (lane == 0) atomicAdd(&cnts[curg], (float)cnt);
            acc = 0.0f; cnt = 0; curg = g;
        }
        float v = OUT2[(size_t)n * 64 + lane] + bv;
        acc += v > 0.0f ? v : 0.0f;
        ++cnt;
    }
    atomicAdd(&pooled[curg * 64 + lane], acc);
    if (lane == 0) atomicAdd(&cnts[curg], (float)cnt);
}

__global__ void k7_fc(const float* __restrict__ pooled, const float* __restrict__ cnts,
                      const float* __restrict__ fcW, const float* __restrict__ fcb,
                      float* __restrict__ out) {
    int g = threadIdx.x;
    if (g >= NG) return;
    float c = fmaxf(cnts[g], 1.0f);
    float o0 = fcb[0], o1 = fcb[1];
    for (int f = 0; f < 64; ++f) {
        float p = pooled[g * 64 + f] / c;
        o0 += p * fcW[f * 2 + 0];
        o1 += p * fcW[f * 2 + 1];
    }
    out[g * 2 + 0] = o0;
    out[g * 2 + 1] = o1;
}

extern "C" void kernel_launch(void* const* d_in, const int* in_sizes, int n_in,
                              void* d_out, int out_size, void* d_ws, size_t ws_size,
                              hipStream_t stream) {
    const float* x    = (const float*)d_in[0];
    const int*   ei   = (const int*)d_in[1];
    const int*   src  = ei;
    const int*   dst  = ei + NE;
    const int*   batch= (const int*)d_in[2];
    const float* W1   = (const float*)d_in[3];
    const float* a1s  = (const float*)d_in[4];
    const float* a1d  = (const float*)d_in[5];
    const float* b1   = (const float*)d_in[6];
    const float* W2   = (const float*)d_in[7];
    const float* a2s  = (const float*)d_in[8];
    const float* a2d  = (const float*)d_in[9];
    const float* b2   = (const float*)d_in[10];
    const float* fcW  = (const float*)d_in[11];
    const float* fcb  = (const float*)d_in[12];
    float* out = (float*)d_out;

    int* deg       = (int*)d_ws;                 // NN
    int* row_start = deg + NN;                   // NN
    int* csr_src   = row_start + NN;             // ET
    half8* H2h     = (half8*)(csr_src + ET);     // NN*64 halfs = NN*32 floats (16B-aligned)
    float* OUT     = (float*)H2h + (size_t)NN * 32;  // NN*64 floats
    float* scoreS  = OUT + (size_t)NN * 64;      // NN
    float* scoreD  = scoreS + NN;                // NN
    float* Y       = scoreD + NN;                // NN
    float2* c12    = (float2*)(Y + NN);          // 1 float2
    float* pooled  = (float*)(c12 + 1);          // NG*64
    float* cnts    = pooled + NG * 64;           // NG
    int*   bcnt    = (int*)(cnts + NG);          // NBUCK*NBLK
    int*   gcnt    = bcnt + NBUCK * NBLK;        // NBUCK
    int*   gbase   = gcnt + NBUCK;               // NBUCK
    int2*  bedge   = (int2*)OUT;                 // alias: ET*8B = 13.6MB <= 25.6MB
                                                 // (dead before k_gat2 writes OUT)

    const int B = 256;
    int gridW = (NN * 64 + B - 1) / B;           // wave-per-node kernels

    // ---- CSR build: two-level LDS counting sort, zero global atomics ----
    k_countA<<<NBLK, B, 0, stream>>>(src, dst, bcnt);
    k_scanrow<<<NBUCK, 64, 0, stream>>>(bcnt, gcnt);
    k_gscan<<<1, 1024, 0, stream>>>(gcnt, gbase);
    k_fillA<<<NBLK, B, 0, stream>>>(src, dst, bcnt, gbase, bedge);
    k_sortB<<<NBUCK, B, 0, stream>>>(gcnt, gbase, bedge, csr_src, deg, row_start);

    // ---- layer 1 (rank-1 scalar path) ----
    k_c1<<<1, 64, 0, stream>>>(W1, a1s, a1d, c12);
    k_gat1<<<gridW, B, 0, stream>>>(row_start, deg, csr_src, x, c12, Y);

    // ---- layer 2 projection (fp16 H2) ----
    k5_h2<<<gridW, B, 0, stream>>>(Y, W1, b1, W2, a2s, a2d, H2h, scoreS, scoreD);

    // ---- layer 2 GAT ----
    k_gat2<<<gridW, B, 0, stream>>>(row_start, deg, csr_src, scoreS, scoreD, H2h, OUT);

    // ---- pool + fc ----
    hipMemsetAsync(pooled, 0, (size_t)(NG * 64 + NG) * 4, stream);
    int gridP = ((NN + POOL_CHUNK - 1) / POOL_CHUNK * 64 + B - 1) / B;
    k6_pool<<<gridP, B, 0, stream>>>(OUT, b2, batch, pooled, cnts);
    k7_fc<<<1, B, 0, stream>>>(pooled, cnts, fcW, fcb, out);
}